// Round 2
// baseline (7804.552 us; speedup 1.0000x reference)
//
#include <hip/hip_runtime.h>
#include <hip/hip_cooperative_groups.h>
#include <math.h>

namespace cg = cooperative_groups;

#define NB 2048
#define ND 512
#define NG 8
#define NITER 64

#define LOG2E 1.4426950408889634f
#define LN2   0.6931471805599453f
#define NEGINF (-__builtin_inff())

__device__ __forceinline__ float fexp2(float x) { return __builtin_amdgcn_exp2f(x); }
__device__ __forceinline__ float flog2(float x) { return __builtin_amdgcn_logf(x); }

// ---- online logsumexp helpers (log2 domain) ----
__device__ __forceinline__ void online1(float& m, float& s, float t) {
  float M = fmaxf(m, t);
  s = fmaf(s, fexp2(m - M), fexp2(t - M));
  m = M;
}
__device__ __forceinline__ void online4(float& m, float& s, float t0, float t1, float t2, float t3) {
  float M4 = fmaxf(fmaxf(t0, t1), fmaxf(t2, t3));
  float M  = fmaxf(m, M4);
  float e = fexp2(t0 - M) + fexp2(t1 - M) + fexp2(t2 - M) + fexp2(t3 - M);
  s = fmaf(s, fexp2(m - M), e);
  m = M;
}
__device__ __forceinline__ void wave_lse_reduce(float& m, float& s) {
  float M = m;
  #pragma unroll
  for (int o = 32; o; o >>= 1) M = fmaxf(M, __shfl_xor(M, o));
  float sv = (M == NEGINF) ? 0.f : s * fexp2(m - M);
  #pragma unroll
  for (int o = 32; o; o >>= 1) sv += __shfl_xor(sv, o);
  m = M; s = sv;
}
__device__ __forceinline__ void group8_lse_reduce(float& m, float& s) {
  float M = m;
  #pragma unroll
  for (int o = 4; o; o >>= 1) M = fmaxf(M, __shfl_xor(M, o, 8));
  float sv = (M == NEGINF) ? 0.f : s * fexp2(m - M);
  #pragma unroll
  for (int o = 4; o; o >>= 1) sv += __shfl_xor(sv, o, 8);
  m = M; s = sv;
}

// ---- setup: O(N) stable counting sort via packed 16-bit scan ----
__global__ __launch_bounds__(256) void k_setup(
    const int* __restrict__ sub_raw,
    int* __restrict__ order, int* __restrict__ pgroup,
    int* __restrict__ counts, int* __restrict__ starts,
    float* __restrict__ lc2, unsigned int* __restrict__ cmax,
    float* __restrict__ gpot, float* __restrict__ f,
    float* __restrict__ fxx0, float* __restrict__ fyy0) {
  __shared__ int subs[NB];
  __shared__ unsigned long long scanLo[256], scanHi[256];
  __shared__ int st[NG + 1];
  __shared__ int odd_nz;
  const int t = threadIdx.x;
  if (t == 0) odd_nz = 0;
  __syncthreads();
  // int64-vs-int32 heuristic: int64 values <8 have zero high words at odd int32 slots
  int nz = 0;
  for (int k = t; k < 1024; k += 256) nz |= (sub_raw[2 * k + 1] != 0) ? 1 : 0;
  if (nz) atomicOr(&odd_nz, 1);
  __syncthreads();
  const int stride = odd_nz ? 1 : 2;
  for (int i = t; i < NB; i += 256) subs[i] = sub_raw[(size_t)i * stride] & 7;
  __syncthreads();
  // per-chunk (8 elems) group counts packed 16b/group into two u64s
  unsigned long long cLo = 0ull, cHi = 0ull;
  #pragma unroll
  for (int k = 0; k < 8; ++k) {
    int g = subs[8 * t + k];
    unsigned long long inc = 1ull << ((g & 3) * 16);
    if (g < 4) cLo += inc; else cHi += inc;
  }
  scanLo[t] = cLo; scanHi[t] = cHi;
  __syncthreads();
  // inclusive Hillis-Steele scan over 256 chunks (no 16-bit carries: sums <= 2048)
  for (int s = 1; s < 256; s <<= 1) {
    unsigned long long aLo = (t >= s) ? scanLo[t - s] : 0ull;
    unsigned long long aHi = (t >= s) ? scanHi[t - s] : 0ull;
    __syncthreads();
    scanLo[t] += aLo; scanHi[t] += aHi;
    __syncthreads();
  }
  if (t == 0) {
    unsigned long long TLo = scanLo[255], THi = scanHi[255];
    int a = 0;
    for (int g = 0; g < NG; ++g) {
      st[g] = a;
      a += (int)(((g < 4 ? TLo : THi) >> ((g & 3) * 16)) & 0xffffull);
    }
    st[NG] = a;
  }
  __syncthreads();
  // exclusive base for my chunk, then stable positions
  unsigned long long bLo = t ? scanLo[t - 1] : 0ull;
  unsigned long long bHi = t ? scanHi[t - 1] : 0ull;
  #pragma unroll
  for (int k = 0; k < 8; ++k) {
    int idx = 8 * t + k;
    int g = subs[idx];
    int sh = (g & 3) * 16;
    unsigned long long cur = (g < 4) ? bLo : bHi;
    int r = (int)((cur >> sh) & 0xffffull);
    int pos = st[g] + r;
    order[pos] = idx;
    pgroup[pos] = g;
    if (g < 4) bLo += 1ull << sh; else bHi += 1ull << sh;
  }
  if (t < NG) {
    int c = st[t + 1] - st[t];
    counts[t] = c;
    int cc = c < 1 ? 1 : c;
    lc2[t] = -flog2((float)cc);   // -log2(cnt_g)
  }
  if (t < NG + 1) starts[t] = st[t];
  if (t == 0) *cmax = 0u;
  for (int i = t; i < NG * NB; i += 256) gpot[i] = 0.f;
  for (int i = t; i < NB; i += 256) { f[i] = 0.f; fxx0[i] = 0.f; fyy0[i] = 0.f; }
}

// ---- permute features by sorted order + row norms ----
__global__ __launch_bounds__(128) void k_permute(
    const float* __restrict__ X, const int* __restrict__ order,
    float* __restrict__ Xp, float* __restrict__ norms) {
  const int i = blockIdx.x, t = threadIdx.x;
  const int src = order[i];
  float4 v = ((const float4*)(X + (size_t)src * ND))[t];
  ((float4*)(Xp + (size_t)i * ND))[t] = v;
  float ss = v.x * v.x + v.y * v.y + v.z * v.z + v.w * v.w;
  #pragma unroll
  for (int o = 32; o; o >>= 1) ss += __shfl_xor(ss, o);
  __shared__ float p[2];
  if ((t & 63) == 0) p[t >> 6] = ss;
  __syncthreads();
  if (t == 0) norms[i] = p[0] + p[1];
}

// ---- C = 0.5*relu(n_i + n_j - 2 Xp Xp^T), plus global max (diam) ----
__global__ __launch_bounds__(256) void k_gemm(
    const float* __restrict__ Xp, const float* __restrict__ norms,
    float* __restrict__ C, unsigned int* __restrict__ cmax) {
  __shared__ __align__(16) float As[32][132];
  __shared__ __align__(16) float Bs[32][132];
  const int t = threadIdx.x;
  const int tx = t & 15, ty = t >> 4;
  const int i0 = blockIdx.y * 128, j0 = blockIdx.x * 128;
  float acc[8][8];
  #pragma unroll
  for (int r = 0; r < 8; ++r)
    #pragma unroll
    for (int c = 0; c < 8; ++c) acc[r][c] = 0.f;
  for (int k0 = 0; k0 < ND; k0 += 32) {
    #pragma unroll
    for (int l = 0; l < 4; ++l) {
      int flat = t + 256 * l;          // 0..1023
      int row = flat >> 3, c4 = flat & 7;
      float4 av = *(const float4*)(Xp + (size_t)(i0 + row) * ND + k0 + c4 * 4);
      As[c4 * 4 + 0][row] = av.x; As[c4 * 4 + 1][row] = av.y;
      As[c4 * 4 + 2][row] = av.z; As[c4 * 4 + 3][row] = av.w;
      float4 bv = *(const float4*)(Xp + (size_t)(j0 + row) * ND + k0 + c4 * 4);
      Bs[c4 * 4 + 0][row] = bv.x; Bs[c4 * 4 + 1][row] = bv.y;
      Bs[c4 * 4 + 2][row] = bv.z; Bs[c4 * 4 + 3][row] = bv.w;
    }
    __syncthreads();
    #pragma unroll
    for (int kk = 0; kk < 32; ++kk) {
      float4 a0 = *(const float4*)&As[kk][ty * 8];
      float4 a1 = *(const float4*)&As[kk][ty * 8 + 4];
      float4 b0 = *(const float4*)&Bs[kk][tx * 8];
      float4 b1 = *(const float4*)&Bs[kk][tx * 8 + 4];
      float aa[8] = {a0.x, a0.y, a0.z, a0.w, a1.x, a1.y, a1.z, a1.w};
      float bb[8] = {b0.x, b0.y, b0.z, b0.w, b1.x, b1.y, b1.z, b1.w};
      #pragma unroll
      for (int r = 0; r < 8; ++r)
        #pragma unroll
        for (int c = 0; c < 8; ++c) acc[r][c] = fmaf(aa[r], bb[c], acc[r][c]);
    }
    __syncthreads();
  }
  float nj[8];
  #pragma unroll
  for (int c = 0; c < 8; ++c) nj[c] = norms[j0 + tx * 8 + c];
  float lmax = 0.f;
  #pragma unroll
  for (int r = 0; r < 8; ++r) {
    const int i = i0 + ty * 8 + r;
    const float ni = norms[i];
    float4 o[2];
    float* op = (float*)o;
    #pragma unroll
    for (int c = 0; c < 8; ++c) {
      float v = 0.5f * fmaxf(ni + nj[c] - 2.f * acc[r][c], 0.f);
      op[c] = v;
      lmax = fmaxf(lmax, v);
    }
    float4* dst = (float4*)(C + (size_t)i * NB + j0 + tx * 8);
    dst[0] = o[0]; dst[1] = o[1];
  }
  #pragma unroll
  for (int o = 32; o; o >>= 1) lmax = fmaxf(lmax, __shfl_xor(lmax, o));
  __shared__ float wmax[4];
  if ((t & 63) == 0) wmax[t >> 6] = lmax;
  __syncthreads();
  if (t == 0) {
    float m = fmaxf(fmaxf(wmax[0], wmax[1]), fmaxf(wmax[2], wmax[3]));
    atomicMax(cmax, __float_as_uint(m));   // C >= 0 so uint compare is order-preserving
  }
}

// ---- persistent cooperative kernel: 64 iterations + finalize ----
// 512 blocks x 4 waves; wave owns row i = blockIdx*4+wave; C row lives in LDS.
__global__ __launch_bounds__(256) void k_loop(
    const float* __restrict__ C, float* __restrict__ f, float* __restrict__ gpot,
    float* __restrict__ fxx0, float* __restrict__ fxx1,
    float* __restrict__ fyy0, float* __restrict__ fyy1,
    const int* __restrict__ pgroup, const int* __restrict__ starts,
    const float* __restrict__ lc2, const unsigned int* __restrict__ cmax,
    const int* __restrict__ counts, float* __restrict__ out) {
  cg::grid_group grid = cg::this_grid();
  __shared__ __align__(16) float sC[4][NB];
  const int wave = threadIdx.x >> 6, lane = threadIdx.x & 63;
  const int i = blockIdx.x * 4 + wave;

  // one-time: C row -> LDS
  {
    const float4* C4 = (const float4*)(C + (size_t)i * NB);
    float4* s4 = (float4*)sC[wave];
    #pragma unroll
    for (int r = 0; r < 8; ++r) s4[r * 64 + lane] = C4[r * 64 + lane];
  }
  __syncthreads();

  const float cm = __uint_as_float(*cmax);
  const float diam = sqrtf(2.f * fmaxf(cm, 1e-12f));
  const int gi = pgroup[i];
  const float lcg1 = lc2[gi];
  const int p1s0 = starts[gi], p1s1 = starts[gi + 1];
  const int gl = lane >> 3, li = lane & 7;
  const float lcg2 = lc2[gl];
  const int p2s0 = starts[gl], p2s1 = starts[gl + 1];
  const float lb2 = -11.0f;  // -log2(2048)

  for (int t = 0; t < NITER; ++t) {
    float sig = fmaxf(diam * fexp2((float)t * -0.15200309344504997f), 0.05f);
    const float eps = sig * sig;
    const float inv2 = LOG2E / eps;
    const float ninv2 = -inv2;
    const float* fxi = (t & 1) ? fxx1 : fxx0;
    float* fxo = (t & 1) ? fxx0 : fxx1;
    const float* fyi = (t & 1) ? fyy1 : fyy0;
    float* fyo = (t & 1) ? fyy0 : fyy1;

    // ---- phase 1: f_new (dense), fyy_new (dense), fxx_new (own segment) ----
    {
      const float4* c4 = (const float4*)sC[wave];
      const float4* g4 = (const float4*)(gpot + (size_t)gi * NB);
      const float4* y4 = (const float4*)fyi;
      float mA = NEGINF, sA = 0.f, mY = NEGINF, sY = 0.f;
      #pragma unroll 2
      for (int r = 0; r < 8; ++r) {
        const int idx = r * 64 + lane;
        float4 c = c4[idx];
        float4 gv = g4[idx];
        float4 yv = y4[idx];
        float c0 = c.x * ninv2, c1 = c.y * ninv2, c2 = c.z * ninv2, c3 = c.w * ninv2;
        online4(mA, sA, fmaf(gv.x, inv2, lb2) + c0, fmaf(gv.y, inv2, lb2) + c1,
                        fmaf(gv.z, inv2, lb2) + c2, fmaf(gv.w, inv2, lb2) + c3);
        online4(mY, sY, fmaf(yv.x, inv2, lb2) + c0, fmaf(yv.y, inv2, lb2) + c1,
                        fmaf(yv.z, inv2, lb2) + c2, fmaf(yv.w, inv2, lb2) + c3);
      }
      float mX = NEGINF, sX = 0.f;
      for (int j = p1s0 + lane; j < p1s1; j += 64)
        online1(mX, sX, fmaf(fxi[j], inv2, lcg1) + sC[wave][j] * ninv2);
      wave_lse_reduce(mA, sA);
      wave_lse_reduce(mY, sY);
      wave_lse_reduce(mX, sX);
      if (lane == 0) {
        f[i]   = -eps * ((mA + flog2(sA)) * LN2);
        fyo[i] = 0.5f * (fyi[i] - eps * ((mY + flog2(sY)) * LN2));
        fxo[i] = 0.5f * (fxi[i] - eps * ((mX + flog2(sX)) * LN2));
      }
    }
    grid.sync();

    // ---- phase 2: g_new[g,i] for all 8 groups (8 lanes per group) ----
    {
      float m = NEGINF, s = 0.f;
      for (int j = p2s0 + li; j < p2s1; j += 8)
        online1(m, s, fmaf(f[j], inv2, lcg2) + sC[wave][j] * ninv2);
      group8_lse_reduce(m, s);
      if (li == 0) gpot[(size_t)gl * NB + i] = -eps * ((m + flog2(s)) * LN2);
    }
    grid.sync();
  }

  // ---- finalize (block 0 only): 25 reductions -> S_g, total ----
  if (blockIdx.x == 0) {
    __shared__ float acc4[4];
    __shared__ float results[25];
    const int tt = threadIdx.x, ln = tt & 63, wid = tt >> 6;
    const float* fxx = fxx0;  // NITER even -> final outputs in buf0
    const float* fyy = fyy0;
    for (int q = 0; q < 25; ++q) {
      float v = 0.f;
      if (q < 8) {
        for (int k = starts[q] + tt; k < starts[q + 1]; k += 256) v += f[k];
      } else if (q < 16) {
        const int g = q - 8;
        for (int k = starts[g] + tt; k < starts[g + 1]; k += 256) v += fxx[k];
      } else if (q < 24) {
        const float* gp = gpot + (size_t)(q - 16) * NB;
        for (int k = tt; k < NB; k += 256) v += gp[k];
      } else {
        for (int k = tt; k < NB; k += 256) v += fyy[k];
      }
      #pragma unroll
      for (int o = 32; o; o >>= 1) v += __shfl_xor(v, o);
      __syncthreads();
      if (ln == 0) acc4[wid] = v;
      __syncthreads();
      if (tt == 0) results[q] = acc4[0] + acc4[1] + acc4[2] + acc4[3];
    }
    __syncthreads();
    if (tt == 0) {
      const float syy = results[24] / (float)NB;
      float tot = 0.f; int nv = 0;
      float sg[8];
      for (int g = 0; g < NG; ++g) {
        float cnt = (float)(counts[g] < 1 ? 1 : counts[g]);
        float S = (results[g] - results[8 + g]) / cnt + results[16 + g] / (float)NB - syy;
        int valid = counts[g] >= 2 ? 1 : 0;
        float sv = valid ? S : 0.f;
        sg[g] = sv;
        if (valid) { tot += sv; nv++; }
      }
      tot /= (float)(nv < 1 ? 1 : nv);
      out[0] = tot;
      for (int g = 0; g < NG; ++g) out[1 + g] = sg[g];
    }
  }
}

extern "C" void kernel_launch(void* const* d_in, const int* in_sizes, int n_in,
                              void* d_out, int out_size, void* d_ws, size_t ws_size,
                              hipStream_t stream) {
  (void)in_sizes; (void)n_in; (void)out_size; (void)ws_size;
  const float* X = (const float*)d_in[0];
  const int* sub = (const int*)d_in[1];

  char* w = (char*)d_ws;
  size_t off = 0;
  auto alloc = [&](size_t bytes) -> void* {
    void* p = w + off;
    off = (off + bytes + 255) & ~(size_t)255;
    return p;
  };
  float* C      = (float*)alloc((size_t)NB * NB * 4);
  float* Xp     = (float*)alloc((size_t)NB * ND * 4);
  float* norms  = (float*)alloc(NB * 4);
  int*   order  = (int*)alloc(NB * 4);
  int*   pgroup = (int*)alloc(NB * 4);
  float* f      = (float*)alloc(NB * 4);
  float* gpot   = (float*)alloc((size_t)NG * NB * 4);
  float* fxx0   = (float*)alloc(NB * 4);
  float* fxx1   = (float*)alloc(NB * 4);
  float* fyy0   = (float*)alloc(NB * 4);
  float* fyy1   = (float*)alloc(NB * 4);
  int*   counts = (int*)alloc(NG * 4);
  int*   starts = (int*)alloc((NG + 1) * 4);
  float* lc2    = (float*)alloc(NG * 4);
  unsigned int* cmax = (unsigned int*)alloc(4);
  float* outp = (float*)d_out;

  k_setup<<<1, 256, 0, stream>>>(sub, order, pgroup, counts, starts, lc2, cmax,
                                 gpot, f, fxx0, fyy0);
  k_permute<<<NB, 128, 0, stream>>>(X, order, Xp, norms);
  k_gemm<<<dim3(16, 16), 256, 0, stream>>>(Xp, norms, C, cmax);

  void* args[] = {
    (void*)&C, (void*)&f, (void*)&gpot,
    (void*)&fxx0, (void*)&fxx1, (void*)&fyy0, (void*)&fyy1,
    (void*)&pgroup, (void*)&starts, (void*)&lc2, (void*)&cmax,
    (void*)&counts, (void*)&outp
  };
  hipLaunchCooperativeKernel((const void*)k_loop, dim3(NB / 4), dim3(256),
                             args, 0, stream);
}

// Round 3
// 1585.549 us; speedup vs baseline: 4.9223x; 4.9223x over previous
//
#include <hip/hip_runtime.h>
#include <math.h>

#define NB 2048
#define ND 512
#define NG 8
#define NITER 64

typedef _Float16 h8 __attribute__((ext_vector_type(8)));

#define LOG2E 1.4426950408889634f
#define LN2   0.6931471805599453f
#define NEGINF (-__builtin_inff())
#define L2_09 -0.15200309344504997f  /* log2(0.9) */

__device__ __forceinline__ float fexp2(float x) { return __builtin_amdgcn_exp2f(x); }
__device__ __forceinline__ float flog2(float x) { return __builtin_amdgcn_logf(x); }

// ---- online logsumexp helpers (log2 domain) ----
__device__ __forceinline__ void online1(float& m, float& s, float t) {
  float M = fmaxf(m, t);
  s = fmaf(s, fexp2(m - M), fexp2(t - M));
  m = M;
}
__device__ __forceinline__ void online4(float& m, float& s, float t0, float t1, float t2, float t3) {
  float M4 = fmaxf(fmaxf(t0, t1), fmaxf(t2, t3));
  float M  = fmaxf(m, M4);
  float e = fexp2(t0 - M) + fexp2(t1 - M) + fexp2(t2 - M) + fexp2(t3 - M);
  s = fmaf(s, fexp2(m - M), e);
  m = M;
}
__device__ __forceinline__ void wave_lse_reduce(float& m, float& s) {
  float M = m;
  #pragma unroll
  for (int o = 32; o; o >>= 1) M = fmaxf(M, __shfl_xor(M, o));
  float sv = (M == NEGINF) ? 0.f : s * fexp2(m - M);
  #pragma unroll
  for (int o = 32; o; o >>= 1) sv += __shfl_xor(sv, o);
  m = M; s = sv;
}

// ---- inline eps schedule: sigma = max(diam*0.9^t, 0.05), eps = sigma^2 ----
__device__ __forceinline__ float eps_at(const unsigned int* cmax, int t) {
  float cm = __uint_as_float(*cmax);
  float diam = sqrtf(2.f * fmaxf(cm, 1e-12f));
  float sig = fmaxf(diam * fexp2((float)t * L2_09), 0.05f);
  return sig * sig;
}

// ---- setup: O(N) stable counting sort via packed 16-bit scan ----
__global__ __launch_bounds__(256) void k_setup(
    const int* __restrict__ sub_raw,
    int* __restrict__ order, int* __restrict__ pgroup,
    int* __restrict__ counts, int* __restrict__ starts,
    float* __restrict__ lc2, unsigned int* __restrict__ cmax,
    float* __restrict__ gpot, float* __restrict__ f,
    float* __restrict__ fxx0, float* __restrict__ fyy0) {
  __shared__ int subs[NB];
  __shared__ unsigned long long scanLo[256], scanHi[256];
  __shared__ int st[NG + 1];
  __shared__ int odd_nz;
  const int t = threadIdx.x;
  if (t == 0) odd_nz = 0;
  __syncthreads();
  // int64-vs-int32 heuristic: int64 values <8 have zero high words at odd int32 slots
  int nz = 0;
  for (int k = t; k < 1024; k += 256) nz |= (sub_raw[2 * k + 1] != 0) ? 1 : 0;
  if (nz) atomicOr(&odd_nz, 1);
  __syncthreads();
  const int stride = odd_nz ? 1 : 2;
  for (int i = t; i < NB; i += 256) subs[i] = sub_raw[(size_t)i * stride] & 7;
  __syncthreads();
  // per-chunk (8 elems) group counts packed 16b/group into two u64s
  unsigned long long cLo = 0ull, cHi = 0ull;
  #pragma unroll
  for (int k = 0; k < 8; ++k) {
    int g = subs[8 * t + k];
    unsigned long long inc = 1ull << ((g & 3) * 16);
    if (g < 4) cLo += inc; else cHi += inc;
  }
  scanLo[t] = cLo; scanHi[t] = cHi;
  __syncthreads();
  // inclusive Hillis-Steele scan over 256 chunks
  for (int s = 1; s < 256; s <<= 1) {
    unsigned long long aLo = (t >= s) ? scanLo[t - s] : 0ull;
    unsigned long long aHi = (t >= s) ? scanHi[t - s] : 0ull;
    __syncthreads();
    scanLo[t] += aLo; scanHi[t] += aHi;
    __syncthreads();
  }
  if (t == 0) {
    unsigned long long TLo = scanLo[255], THi = scanHi[255];
    int a = 0;
    for (int g = 0; g < NG; ++g) {
      st[g] = a;
      a += (int)(((g < 4 ? TLo : THi) >> ((g & 3) * 16)) & 0xffffull);
    }
    st[NG] = a;
  }
  __syncthreads();
  unsigned long long bLo = t ? scanLo[t - 1] : 0ull;
  unsigned long long bHi = t ? scanHi[t - 1] : 0ull;
  #pragma unroll
  for (int k = 0; k < 8; ++k) {
    int idx = 8 * t + k;
    int g = subs[idx];
    int sh = (g & 3) * 16;
    unsigned long long cur = (g < 4) ? bLo : bHi;
    int r = (int)((cur >> sh) & 0xffffull);
    int pos = st[g] + r;
    order[pos] = idx;
    pgroup[pos] = g;
    if (g < 4) bLo += 1ull << sh; else bHi += 1ull << sh;
  }
  if (t < NG) {
    int c = st[t + 1] - st[t];
    counts[t] = c;
    int cc = c < 1 ? 1 : c;
    lc2[t] = -flog2((float)cc);   // -log2(cnt_g)
  }
  if (t < NG + 1) starts[t] = st[t];
  if (t == 0) *cmax = 0u;
  for (int i = t; i < NG * NB; i += 256) gpot[i] = 0.f;
  for (int i = t; i < NB; i += 256) { f[i] = 0.f; fxx0[i] = 0.f; fyy0[i] = 0.f; }
}

// ---- permute features by sorted order + row norms ----
__global__ __launch_bounds__(128) void k_permute(
    const float* __restrict__ X, const int* __restrict__ order,
    float* __restrict__ Xp, float* __restrict__ norms) {
  const int i = blockIdx.x, t = threadIdx.x;
  const int src = order[i];
  float4 v = ((const float4*)(X + (size_t)src * ND))[t];
  ((float4*)(Xp + (size_t)i * ND))[t] = v;
  float ss = v.x * v.x + v.y * v.y + v.z * v.z + v.w * v.w;
  #pragma unroll
  for (int o = 32; o; o >>= 1) ss += __shfl_xor(ss, o);
  __shared__ float p[2];
  if ((t & 63) == 0) p[t >> 6] = ss;
  __syncthreads();
  if (t == 0) norms[i] = p[0] + p[1];
}

// ---- C = fp16(0.5*relu(n_i + n_j - 2 Xp Xp^T)), plus global max (diam) ----
__global__ __launch_bounds__(256) void k_gemm(
    const float* __restrict__ Xp, const float* __restrict__ norms,
    _Float16* __restrict__ C, unsigned int* __restrict__ cmax) {
  __shared__ __align__(16) float As[32][132];
  __shared__ __align__(16) float Bs[32][132];
  const int t = threadIdx.x;
  const int tx = t & 15, ty = t >> 4;
  const int i0 = blockIdx.y * 128, j0 = blockIdx.x * 128;
  float acc[8][8];
  #pragma unroll
  for (int r = 0; r < 8; ++r)
    #pragma unroll
    for (int c = 0; c < 8; ++c) acc[r][c] = 0.f;
  for (int k0 = 0; k0 < ND; k0 += 32) {
    #pragma unroll
    for (int l = 0; l < 4; ++l) {
      int flat = t + 256 * l;          // 0..1023
      int row = flat >> 3, c4 = flat & 7;
      float4 av = *(const float4*)(Xp + (size_t)(i0 + row) * ND + k0 + c4 * 4);
      As[c4 * 4 + 0][row] = av.x; As[c4 * 4 + 1][row] = av.y;
      As[c4 * 4 + 2][row] = av.z; As[c4 * 4 + 3][row] = av.w;
      float4 bv = *(const float4*)(Xp + (size_t)(j0 + row) * ND + k0 + c4 * 4);
      Bs[c4 * 4 + 0][row] = bv.x; Bs[c4 * 4 + 1][row] = bv.y;
      Bs[c4 * 4 + 2][row] = bv.z; Bs[c4 * 4 + 3][row] = bv.w;
    }
    __syncthreads();
    #pragma unroll
    for (int kk = 0; kk < 32; ++kk) {
      float4 a0 = *(const float4*)&As[kk][ty * 8];
      float4 a1 = *(const float4*)&As[kk][ty * 8 + 4];
      float4 b0 = *(const float4*)&Bs[kk][tx * 8];
      float4 b1 = *(const float4*)&Bs[kk][tx * 8 + 4];
      float aa[8] = {a0.x, a0.y, a0.z, a0.w, a1.x, a1.y, a1.z, a1.w};
      float bb[8] = {b0.x, b0.y, b0.z, b0.w, b1.x, b1.y, b1.z, b1.w};
      #pragma unroll
      for (int r = 0; r < 8; ++r)
        #pragma unroll
        for (int c = 0; c < 8; ++c) acc[r][c] = fmaf(aa[r], bb[c], acc[r][c]);
    }
    __syncthreads();
  }
  float nj[8];
  #pragma unroll
  for (int c = 0; c < 8; ++c) nj[c] = norms[j0 + tx * 8 + c];
  float lmax = 0.f;
  #pragma unroll
  for (int r = 0; r < 8; ++r) {
    const int i = i0 + ty * 8 + r;
    const float ni = norms[i];
    h8 hv;
    #pragma unroll
    for (int c = 0; c < 8; ++c) {
      float v = 0.5f * fmaxf(ni + nj[c] - 2.f * acc[r][c], 0.f);
      hv[c] = (_Float16)v;
      lmax = fmaxf(lmax, v);
    }
    *(h8*)(C + (size_t)i * NB + j0 + tx * 8) = hv;
  }
  #pragma unroll
  for (int o = 32; o; o >>= 1) lmax = fmaxf(lmax, __shfl_xor(lmax, o));
  __shared__ float wmax[4];
  if ((t & 63) == 0) wmax[t >> 6] = lmax;
  __syncthreads();
  if (t == 0) {
    float m = fmaxf(fmaxf(wmax[0], wmax[1]), fmaxf(wmax[2], wmax[3]));
    atomicMax(cmax, __float_as_uint(m));   // C >= 0 so uint compare is order-preserving
  }
}

// ---- pass1: f_new (dense), fxx_new (own segment), fyy_new (dense); 1 wave / row ----
__global__ __launch_bounds__(256) void k_pass1(
    const _Float16* __restrict__ C, const float* __restrict__ gpot,
    const float* __restrict__ fxx_in, const float* __restrict__ fyy_in,
    float* __restrict__ f_out, float* __restrict__ fxx_out, float* __restrict__ fyy_out,
    const int* __restrict__ pgroup, const int* __restrict__ starts,
    const float* __restrict__ lc2, const unsigned int* __restrict__ cmax, int iter) {
  const int wave = threadIdx.x >> 6, lane = threadIdx.x & 63;
  const int i = blockIdx.x * 4 + wave;
  const float eps = eps_at(cmax, iter);
  const float inv2 = LOG2E / eps;
  const float ninv2 = -inv2;
  const int gi = pgroup[i];
  const float lb2 = -11.0f;  // -log2(2048)
  const _Float16* Crow = C + (size_t)i * NB;
  const float* gr = gpot + (size_t)gi * NB;
  float mA = NEGINF, sA = 0.f, mY = NEGINF, sY = 0.f;
  #pragma unroll
  for (int r = 0; r < 4; ++r) {
    const int j0 = r * 512 + lane * 8;
    h8 ch = *(const h8*)(Crow + j0);
    float4 g0 = *(const float4*)(gr + j0);
    float4 g1 = *(const float4*)(gr + j0 + 4);
    float4 y0 = *(const float4*)(fyy_in + j0);
    float4 y1 = *(const float4*)(fyy_in + j0 + 4);
    float c0 = (float)ch[0] * ninv2, c1 = (float)ch[1] * ninv2;
    float c2 = (float)ch[2] * ninv2, c3 = (float)ch[3] * ninv2;
    float c4 = (float)ch[4] * ninv2, c5 = (float)ch[5] * ninv2;
    float c6 = (float)ch[6] * ninv2, c7 = (float)ch[7] * ninv2;
    online4(mA, sA, fmaf(g0.x, inv2, lb2) + c0, fmaf(g0.y, inv2, lb2) + c1,
                    fmaf(g0.z, inv2, lb2) + c2, fmaf(g0.w, inv2, lb2) + c3);
    online4(mA, sA, fmaf(g1.x, inv2, lb2) + c4, fmaf(g1.y, inv2, lb2) + c5,
                    fmaf(g1.z, inv2, lb2) + c6, fmaf(g1.w, inv2, lb2) + c7);
    online4(mY, sY, fmaf(y0.x, inv2, lb2) + c0, fmaf(y0.y, inv2, lb2) + c1,
                    fmaf(y0.z, inv2, lb2) + c2, fmaf(y0.w, inv2, lb2) + c3);
    online4(mY, sY, fmaf(y1.x, inv2, lb2) + c4, fmaf(y1.y, inv2, lb2) + c5,
                    fmaf(y1.z, inv2, lb2) + c6, fmaf(y1.w, inv2, lb2) + c7);
  }
  const float lcg = lc2[gi];
  const int s0 = starts[gi], s1 = starts[gi + 1];
  float mX = NEGINF, sX = 0.f;
  for (int j = s0 + lane; j < s1; j += 64)
    online1(mX, sX, fmaf(fxx_in[j], inv2, lcg) + (float)Crow[j] * ninv2);
  wave_lse_reduce(mA, sA);
  wave_lse_reduce(mY, sY);
  wave_lse_reduce(mX, sX);
  if (lane == 0) {
    f_out[i]   = -eps * ((mA + flog2(sA)) * LN2);
    fyy_out[i] = 0.5f * (fyy_in[i] - eps * ((mY + flog2(sY)) * LN2));
    fxx_out[i] = 0.5f * (fxx_in[i] - eps * ((mX + flog2(sX)) * LN2));
  }
}

// ---- pass2: g_new[g,i] for all g; full wave per group (coalesced); 1 wave / row ----
__global__ __launch_bounds__(256) void k_pass2(
    const _Float16* __restrict__ C, const float* __restrict__ f,
    float* __restrict__ gpot, const int* __restrict__ starts,
    const float* __restrict__ lc2, const unsigned int* __restrict__ cmax, int iter) {
  const int wave = threadIdx.x >> 6, lane = threadIdx.x & 63;
  const int i = blockIdx.x * 4 + wave;
  const float eps = eps_at(cmax, iter);
  const float inv2 = LOG2E / eps;
  const float ninv2 = -inv2;
  const _Float16* Crow = C + (size_t)i * NB;
  for (int gl = 0; gl < NG; ++gl) {
    const float lcg = lc2[gl];
    const int s0 = starts[gl], s1 = starts[gl + 1];
    float m = NEGINF, s = 0.f;
    for (int j = s0 + lane; j < s1; j += 64)
      online1(m, s, fmaf(f[j], inv2, lcg) + (float)Crow[j] * ninv2);
    wave_lse_reduce(m, s);
    if (lane == 0) gpot[(size_t)gl * NB + i] = -eps * ((m + flog2(s)) * LN2);
  }
}

// ---- finalize: 25 reductions -> S_g, total ----
__global__ __launch_bounds__(256) void k_final(
    const float* __restrict__ f, const float* __restrict__ gpot,
    const float* __restrict__ fxx, const float* __restrict__ fyy,
    const int* __restrict__ counts, const int* __restrict__ starts,
    float* __restrict__ out) {
  __shared__ float acc4[4];
  __shared__ float results[25];
  const int t = threadIdx.x, lane = t & 63, wid = t >> 6;
  for (int q = 0; q < 25; ++q) {
    float v = 0.f;
    if (q < 8) {
      for (int i = starts[q] + t; i < starts[q + 1]; i += 256) v += f[i];
    } else if (q < 16) {
      const int g = q - 8;
      for (int i = starts[g] + t; i < starts[g + 1]; i += 256) v += fxx[i];
    } else if (q < 24) {
      const float* gp = gpot + (size_t)(q - 16) * NB;
      for (int i = t; i < NB; i += 256) v += gp[i];
    } else {
      for (int i = t; i < NB; i += 256) v += fyy[i];
    }
    #pragma unroll
    for (int o = 32; o; o >>= 1) v += __shfl_xor(v, o);
    __syncthreads();
    if (lane == 0) acc4[wid] = v;
    __syncthreads();
    if (t == 0) results[q] = acc4[0] + acc4[1] + acc4[2] + acc4[3];
  }
  __syncthreads();
  if (t == 0) {
    const float syy = results[24] / (float)NB;
    float tot = 0.f; int nv = 0;
    float sg[8];
    for (int g = 0; g < NG; ++g) {
      float cnt = (float)(counts[g] < 1 ? 1 : counts[g]);
      float S = (results[g] - results[8 + g]) / cnt + results[16 + g] / (float)NB - syy;
      int valid = counts[g] >= 2 ? 1 : 0;
      float sv = valid ? S : 0.f;
      sg[g] = sv;
      if (valid) { tot += sv; nv++; }
    }
    tot /= (float)(nv < 1 ? 1 : nv);
    out[0] = tot;
    for (int g = 0; g < NG; ++g) out[1 + g] = sg[g];
  }
}

extern "C" void kernel_launch(void* const* d_in, const int* in_sizes, int n_in,
                              void* d_out, int out_size, void* d_ws, size_t ws_size,
                              hipStream_t stream) {
  (void)in_sizes; (void)n_in; (void)out_size; (void)ws_size;
  const float* X = (const float*)d_in[0];
  const int* sub = (const int*)d_in[1];

  char* w = (char*)d_ws;
  size_t off = 0;
  auto alloc = [&](size_t bytes) -> void* {
    void* p = w + off;
    off = (off + bytes + 255) & ~(size_t)255;
    return p;
  };
  _Float16* C   = (_Float16*)alloc((size_t)NB * NB * 2);
  float* Xp     = (float*)alloc((size_t)NB * ND * 4);
  float* norms  = (float*)alloc(NB * 4);
  int*   order  = (int*)alloc(NB * 4);
  int*   pgroup = (int*)alloc(NB * 4);
  float* f      = (float*)alloc(NB * 4);
  float* gpot   = (float*)alloc((size_t)NG * NB * 4);
  float* fxx0   = (float*)alloc(NB * 4);
  float* fxx1   = (float*)alloc(NB * 4);
  float* fyy0   = (float*)alloc(NB * 4);
  float* fyy1   = (float*)alloc(NB * 4);
  int*   counts = (int*)alloc(NG * 4);
  int*   starts = (int*)alloc((NG + 1) * 4);
  float* lc2    = (float*)alloc(NG * 4);
  unsigned int* cmax = (unsigned int*)alloc(4);

  k_setup<<<1, 256, 0, stream>>>(sub, order, pgroup, counts, starts, lc2, cmax,
                                 gpot, f, fxx0, fyy0);
  k_permute<<<NB, 128, 0, stream>>>(X, order, Xp, norms);
  k_gemm<<<dim3(16, 16), 256, 0, stream>>>(Xp, norms, C, cmax);
  for (int it = 0; it < NITER; ++it) {
    float* fxi = (it & 1) ? fxx1 : fxx0;
    float* fxo = (it & 1) ? fxx0 : fxx1;
    float* fyi = (it & 1) ? fyy1 : fyy0;
    float* fyo = (it & 1) ? fyy0 : fyy1;
    k_pass1<<<NB / 4, 256, 0, stream>>>(C, gpot, fxi, fyi, f, fxo, fyo,
                                        pgroup, starts, lc2, cmax, it);
    k_pass2<<<NB / 4, 256, 0, stream>>>(C, f, gpot, starts, lc2, cmax, it);
  }
  // after it=63 (odd), outputs landed in fxx0 / fyy0
  k_final<<<1, 256, 0, stream>>>(f, gpot, fxx0, fyy0, counts, starts, (float*)d_out);
}

// Round 4
// 1236.454 us; speedup vs baseline: 6.3120x; 1.2823x over previous
//
#include <hip/hip_runtime.h>
#include <math.h>

#define NB 2048
#define ND 512
#define NG 8
#define NITER 64

typedef _Float16 h8 __attribute__((ext_vector_type(8)));
typedef short bf16x8 __attribute__((ext_vector_type(8)));
typedef short us4 __attribute__((ext_vector_type(4)));
typedef float f32x4 __attribute__((ext_vector_type(4)));

#define LOG2E 1.4426950408889634f
#define LN2   0.6931471805599453f
#define NEGINF (-__builtin_inff())
#define L2_09 -0.15200309344504997f  /* log2(0.9) */

__device__ __forceinline__ float fexp2(float x) { return __builtin_amdgcn_exp2f(x); }
__device__ __forceinline__ float flog2(float x) { return __builtin_amdgcn_logf(x); }

__device__ __forceinline__ unsigned short f2bf(float x) {
  unsigned u = __float_as_uint(x);
  unsigned r = u + 0x7fff + ((u >> 16) & 1);
  return (unsigned short)(r >> 16);
}
__device__ __forceinline__ float bf2f(unsigned short h) {
  return __uint_as_float(((unsigned)h) << 16);
}

__device__ __forceinline__ void online1(float& m, float& s, float t) {
  float M = fmaxf(m, t);
  s = fmaf(s, fexp2(m - M), fexp2(t - M));
  m = M;
}
__device__ __forceinline__ float wave_max(float v) {
  #pragma unroll
  for (int o = 32; o; o >>= 1) v = fmaxf(v, __shfl_xor(v, o));
  return v;
}
__device__ __forceinline__ float wave_sum(float v) {
  #pragma unroll
  for (int o = 32; o; o >>= 1) v += __shfl_xor(v, o);
  return v;
}
__device__ __forceinline__ void wave_lse_reduce(float& m, float& s) {
  float M = m;
  #pragma unroll
  for (int o = 32; o; o >>= 1) M = fmaxf(M, __shfl_xor(M, o));
  float sv = (M == NEGINF) ? 0.f : s * fexp2(m - M);
  #pragma unroll
  for (int o = 32; o; o >>= 1) sv += __shfl_xor(sv, o);
  m = M; s = sv;
}
__device__ __forceinline__ void group8_lse_reduce(float& m, float& s) {
  float M = m;
  #pragma unroll
  for (int o = 4; o; o >>= 1) M = fmaxf(M, __shfl_xor(M, o, 8));
  float sv = (M == NEGINF) ? 0.f : s * fexp2(m - M);
  #pragma unroll
  for (int o = 4; o; o >>= 1) sv += __shfl_xor(sv, o, 8);
  m = M; s = sv;
}

// ---- inline eps schedule ----
__device__ __forceinline__ float eps_at(const unsigned int* cmax, int t) {
  float cm = __uint_as_float(*cmax);
  float diam = sqrtf(2.f * fmaxf(cm, 1e-12f));
  float sig = fmaxf(diam * fexp2((float)t * L2_09), 0.05f);
  return sig * sig;
}

// ---- setup: O(N) stable counting sort via packed 16-bit scan ----
__global__ __launch_bounds__(256) void k_setup(
    const int* __restrict__ sub_raw,
    int* __restrict__ order, int* __restrict__ pgroup,
    int* __restrict__ counts, int* __restrict__ starts,
    float* __restrict__ lc2, unsigned int* __restrict__ cmax,
    float* __restrict__ gpot, float* __restrict__ f,
    float* __restrict__ fxx0, float* __restrict__ fyy0) {
  __shared__ int subs[NB];
  __shared__ unsigned long long scanLo[256], scanHi[256];
  __shared__ int st[NG + 1];
  __shared__ int odd_nz;
  const int t = threadIdx.x;
  if (t == 0) odd_nz = 0;
  __syncthreads();
  int nz = 0;
  for (int k = t; k < 1024; k += 256) nz |= (sub_raw[2 * k + 1] != 0) ? 1 : 0;
  if (nz) atomicOr(&odd_nz, 1);
  __syncthreads();
  const int stride = odd_nz ? 1 : 2;
  for (int i = t; i < NB; i += 256) subs[i] = sub_raw[(size_t)i * stride] & 7;
  __syncthreads();
  unsigned long long cLo = 0ull, cHi = 0ull;
  #pragma unroll
  for (int k = 0; k < 8; ++k) {
    int g = subs[8 * t + k];
    unsigned long long inc = 1ull << ((g & 3) * 16);
    if (g < 4) cLo += inc; else cHi += inc;
  }
  scanLo[t] = cLo; scanHi[t] = cHi;
  __syncthreads();
  for (int s = 1; s < 256; s <<= 1) {
    unsigned long long aLo = (t >= s) ? scanLo[t - s] : 0ull;
    unsigned long long aHi = (t >= s) ? scanHi[t - s] : 0ull;
    __syncthreads();
    scanLo[t] += aLo; scanHi[t] += aHi;
    __syncthreads();
  }
  if (t == 0) {
    unsigned long long TLo = scanLo[255], THi = scanHi[255];
    int a = 0;
    for (int g = 0; g < NG; ++g) {
      st[g] = a;
      a += (int)(((g < 4 ? TLo : THi) >> ((g & 3) * 16)) & 0xffffull);
    }
    st[NG] = a;
  }
  __syncthreads();
  unsigned long long bLo = t ? scanLo[t - 1] : 0ull;
  unsigned long long bHi = t ? scanHi[t - 1] : 0ull;
  #pragma unroll
  for (int k = 0; k < 8; ++k) {
    int idx = 8 * t + k;
    int g = subs[idx];
    int sh = (g & 3) * 16;
    unsigned long long cur = (g < 4) ? bLo : bHi;
    int r = (int)((cur >> sh) & 0xffffull);
    int pos = st[g] + r;
    order[pos] = idx;
    pgroup[pos] = g;
    if (g < 4) bLo += 1ull << sh; else bHi += 1ull << sh;
  }
  if (t < NG) {
    int c = st[t + 1] - st[t];
    counts[t] = c;
    int cc = c < 1 ? 1 : c;
    lc2[t] = -flog2((float)cc);
  }
  if (t < NG + 1) starts[t] = st[t];
  if (t == 0) *cmax = 0u;
  {
    float4* g4 = (float4*)gpot;
    for (int i = t; i < NG * NB / 4; i += 256) g4[i] = make_float4(0.f, 0.f, 0.f, 0.f);
  }
  for (int i = t; i < NB; i += 256) { f[i] = 0.f; fxx0[i] = 0.f; fyy0[i] = 0.f; }
}

// ---- permute + split into bf16 hi/lo + row norms (norms from exact f32) ----
__global__ __launch_bounds__(128) void k_permute(
    const float* __restrict__ X, const int* __restrict__ order,
    unsigned short* __restrict__ Xhi, unsigned short* __restrict__ Xlo,
    float* __restrict__ norms) {
  const int i = blockIdx.x, t = threadIdx.x;
  const int src = order[i];
  float4 v = ((const float4*)(X + (size_t)src * ND))[t];
  float vv[4] = {v.x, v.y, v.z, v.w};
  unsigned short h[4], l[4];
  #pragma unroll
  for (int e = 0; e < 4; ++e) {
    h[e] = f2bf(vv[e]);
    l[e] = f2bf(vv[e] - bf2f(h[e]));
  }
  us4 hv = { (short)h[0], (short)h[1], (short)h[2], (short)h[3] };
  us4 lv = { (short)l[0], (short)l[1], (short)l[2], (short)l[3] };
  *(us4*)(Xhi + (size_t)i * ND + t * 4) = hv;
  *(us4*)(Xlo + (size_t)i * ND + t * 4) = lv;
  float ss = v.x * v.x + v.y * v.y + v.z * v.z + v.w * v.w;
  #pragma unroll
  for (int o = 32; o; o >>= 1) ss += __shfl_xor(ss, o);
  __shared__ float p[2];
  if ((t & 63) == 0) p[t >> 6] = ss;
  __syncthreads();
  if (t == 0) norms[i] = p[0] + p[1];
}

// ---- C = fp16(0.5*relu(n_i + n_j - 2 X X^T)) via split-bf16 MFMA + global max ----
__global__ __launch_bounds__(256, 1) void k_gemm(
    const unsigned short* __restrict__ Xhi, const unsigned short* __restrict__ Xlo,
    const float* __restrict__ norms, _Float16* __restrict__ C,
    unsigned int* __restrict__ cmax) {
  __shared__ unsigned short Ah[128][40], Al[128][40], Bh[128][40], Bl[128][40];
  const int t = threadIdx.x;
  const int wave = t >> 6, lane = t & 63;
  const int wm = wave >> 1, wn = wave & 1;
  const int i0 = blockIdx.y * 128, j0 = blockIdx.x * 128;
  const int srow = t >> 1, shalf = t & 1;
  const size_t gAoff = (size_t)(i0 + srow) * ND + shalf * 16;
  const size_t gBoff = (size_t)(j0 + srow) * ND + shalf * 16;
  const int fr = lane & 15, fo = (lane >> 4) * 8;

  f32x4 acc[4][4];
  #pragma unroll
  for (int mi = 0; mi < 4; ++mi)
    #pragma unroll
    for (int ni = 0; ni < 4; ++ni) acc[mi][ni] = (f32x4){0.f, 0.f, 0.f, 0.f};

  for (int kc = 0; kc < ND; kc += 32) {
    // stage 4 tiles (128x32 bf16 each), row padded to 40 elems
    bf16x8 a0 = *(const bf16x8*)(Xhi + gAoff + kc);
    bf16x8 a1 = *(const bf16x8*)(Xhi + gAoff + kc + 8);
    bf16x8 a2 = *(const bf16x8*)(Xlo + gAoff + kc);
    bf16x8 a3 = *(const bf16x8*)(Xlo + gAoff + kc + 8);
    bf16x8 b0 = *(const bf16x8*)(Xhi + gBoff + kc);
    bf16x8 b1 = *(const bf16x8*)(Xhi + gBoff + kc + 8);
    bf16x8 b2 = *(const bf16x8*)(Xlo + gBoff + kc);
    bf16x8 b3 = *(const bf16x8*)(Xlo + gBoff + kc + 8);
    *(bf16x8*)&Ah[srow][shalf * 16] = a0;
    *(bf16x8*)&Ah[srow][shalf * 16 + 8] = a1;
    *(bf16x8*)&Al[srow][shalf * 16] = a2;
    *(bf16x8*)&Al[srow][shalf * 16 + 8] = a3;
    *(bf16x8*)&Bh[srow][shalf * 16] = b0;
    *(bf16x8*)&Bh[srow][shalf * 16 + 8] = b1;
    *(bf16x8*)&Bl[srow][shalf * 16] = b2;
    *(bf16x8*)&Bl[srow][shalf * 16 + 8] = b3;
    __syncthreads();

    bf16x8 fah[4], fal[4], fbh[4], fbl[4];
    #pragma unroll
    for (int mi = 0; mi < 4; ++mi) {
      fah[mi] = *(const bf16x8*)&Ah[wm * 64 + mi * 16 + fr][fo];
      fal[mi] = *(const bf16x8*)&Al[wm * 64 + mi * 16 + fr][fo];
    }
    #pragma unroll
    for (int ni = 0; ni < 4; ++ni) {
      fbh[ni] = *(const bf16x8*)&Bh[wn * 64 + ni * 16 + fr][fo];
      fbl[ni] = *(const bf16x8*)&Bl[wn * 64 + ni * 16 + fr][fo];
    }
    #pragma unroll
    for (int mi = 0; mi < 4; ++mi)
      #pragma unroll
      for (int ni = 0; ni < 4; ++ni) {
        acc[mi][ni] = __builtin_amdgcn_mfma_f32_16x16x32_bf16(fah[mi], fbh[ni], acc[mi][ni], 0, 0, 0);
        acc[mi][ni] = __builtin_amdgcn_mfma_f32_16x16x32_bf16(fah[mi], fbl[ni], acc[mi][ni], 0, 0, 0);
        acc[mi][ni] = __builtin_amdgcn_mfma_f32_16x16x32_bf16(fal[mi], fbh[ni], acc[mi][ni], 0, 0, 0);
      }
    __syncthreads();
  }

  // epilogue: D[m][n]: row = (lane>>4)*4 + reg, col = lane&15
  const int dr = (lane >> 4) * 4, dc = lane & 15;
  float njn[4];
  #pragma unroll
  for (int ni = 0; ni < 4; ++ni) njn[ni] = norms[j0 + wn * 64 + ni * 16 + dc];
  float lmax = 0.f;
  #pragma unroll
  for (int mi = 0; mi < 4; ++mi) {
    const int rbase = i0 + wm * 64 + mi * 16 + dr;
    float4 nin = *(const float4*)(norms + rbase);
    float nin4[4] = {nin.x, nin.y, nin.z, nin.w};
    #pragma unroll
    for (int ni = 0; ni < 4; ++ni) {
      const int cbase = j0 + wn * 64 + ni * 16 + dc;
      #pragma unroll
      for (int reg = 0; reg < 4; ++reg) {
        float v = 0.5f * fmaxf(nin4[reg] + njn[ni] - 2.f * acc[mi][ni][reg], 0.f);
        C[(size_t)(rbase + reg) * NB + cbase] = (_Float16)v;
        lmax = fmaxf(lmax, v);
      }
    }
  }
  lmax = wave_max(lmax);
  __shared__ float wmax[4];
  if (lane == 0) wmax[wave] = lmax;
  __syncthreads();
  if (t == 0) {
    float m = fmaxf(fmaxf(wmax[0], wmax[1]), fmaxf(wmax[2], wmax[3]));
    atomicMax(cmax, __float_as_uint(m));
  }
}

// ---- pass1: max-then-sum; 1 wave / row ----
__global__ __launch_bounds__(256) void k_pass1(
    const _Float16* __restrict__ C, const float* __restrict__ gpot,
    const float* __restrict__ fxx_in, const float* __restrict__ fyy_in,
    float* __restrict__ f_out, float* __restrict__ fxx_out, float* __restrict__ fyy_out,
    const int* __restrict__ pgroup, const int* __restrict__ starts,
    const float* __restrict__ lc2, const unsigned int* __restrict__ cmax, int iter) {
  const int wave = threadIdx.x >> 6, lane = threadIdx.x & 63;
  const int i = blockIdx.x * 4 + wave;
  const float eps = eps_at(cmax, iter);
  const float inv2 = LOG2E / eps;
  const float ninv2 = -inv2;
  const int gi = pgroup[i];
  const float lb2 = -11.0f;  // -log2(2048)
  const _Float16* Crow = C + (size_t)i * NB;
  const float* gr = gpot + (size_t)gi * NB;

  float tA[32], tY[32];
  #pragma unroll
  for (int r = 0; r < 4; ++r) {
    const int j0 = r * 512 + lane * 8;
    h8 ch = *(const h8*)(Crow + j0);
    float4 g0 = *(const float4*)(gr + j0);
    float4 g1 = *(const float4*)(gr + j0 + 4);
    float4 y0 = *(const float4*)(fyy_in + j0);
    float4 y1 = *(const float4*)(fyy_in + j0 + 4);
    float gv[8] = {g0.x, g0.y, g0.z, g0.w, g1.x, g1.y, g1.z, g1.w};
    float yv[8] = {y0.x, y0.y, y0.z, y0.w, y1.x, y1.y, y1.z, y1.w};
    #pragma unroll
    for (int e = 0; e < 8; ++e) {
      float ci = fmaf((float)ch[e], ninv2, lb2);
      tA[r * 8 + e] = fmaf(gv[e], inv2, ci);
      tY[r * 8 + e] = fmaf(yv[e], inv2, ci);
    }
  }
  // 4-chain tree max, then wave max
  float a0 = NEGINF, a1 = NEGINF, a2 = NEGINF, a3 = NEGINF;
  float b0 = NEGINF, b1 = NEGINF, b2 = NEGINF, b3 = NEGINF;
  #pragma unroll
  for (int k = 0; k < 32; k += 4) {
    a0 = fmaxf(a0, tA[k]); a1 = fmaxf(a1, tA[k + 1]);
    a2 = fmaxf(a2, tA[k + 2]); a3 = fmaxf(a3, tA[k + 3]);
    b0 = fmaxf(b0, tY[k]); b1 = fmaxf(b1, tY[k + 1]);
    b2 = fmaxf(b2, tY[k + 2]); b3 = fmaxf(b3, tY[k + 3]);
  }
  const float mA = wave_max(fmaxf(fmaxf(a0, a1), fmaxf(a2, a3)));
  const float mY = wave_max(fmaxf(fmaxf(b0, b1), fmaxf(b2, b3)));
  // independent exp2 sums (no rescale chain)
  float s0 = 0.f, s1 = 0.f, s2 = 0.f, s3 = 0.f;
  float u0 = 0.f, u1 = 0.f, u2 = 0.f, u3 = 0.f;
  #pragma unroll
  for (int k = 0; k < 32; k += 4) {
    s0 += fexp2(tA[k] - mA); s1 += fexp2(tA[k + 1] - mA);
    s2 += fexp2(tA[k + 2] - mA); s3 += fexp2(tA[k + 3] - mA);
    u0 += fexp2(tY[k] - mY); u1 += fexp2(tY[k + 1] - mY);
    u2 += fexp2(tY[k + 2] - mY); u3 += fexp2(tY[k + 3] - mY);
  }
  const float sA = wave_sum((s0 + s1) + (s2 + s3));
  const float sY = wave_sum((u0 + u1) + (u2 + u3));
  // fxx: own segment only
  const float lcg = lc2[gi];
  const int seg0 = starts[gi], seg1 = starts[gi + 1];
  float mX = NEGINF, sX = 0.f;
  for (int j = seg0 + lane; j < seg1; j += 64)
    online1(mX, sX, fmaf(fxx_in[j], inv2, lcg) + (float)Crow[j] * ninv2);
  wave_lse_reduce(mX, sX);
  if (lane == 0) {
    f_out[i]   = -eps * ((mA + flog2(sA)) * LN2);
    fyy_out[i] = 0.5f * (fyy_in[i] - eps * ((mY + flog2(sY)) * LN2));
    fxx_out[i] = 0.5f * (fxx_in[i] - eps * ((mX + flog2(sX)) * LN2));
  }
}

// ---- pass2: octet layout, max-then-sum, fixed unroll + cleanup ----
#define KMAX 40
__global__ __launch_bounds__(256) void k_pass2(
    const _Float16* __restrict__ C, const float* __restrict__ f,
    float* __restrict__ gpot, const int* __restrict__ starts,
    const float* __restrict__ lc2, const unsigned int* __restrict__ cmax, int iter) {
  const int wave = threadIdx.x >> 6, lane = threadIdx.x & 63;
  const int i = blockIdx.x * 4 + wave;
  const float eps = eps_at(cmax, iter);
  const float inv2 = LOG2E / eps;
  const float ninv2 = -inv2;
  const _Float16* Crow = C + (size_t)i * NB;
  const int gl = lane >> 3, li = lane & 7;
  const float lcg = lc2[gl];
  const int seg0 = starts[gl], seg1 = starts[gl + 1];

  float tv[KMAX];
  #pragma unroll
  for (int k = 0; k < KMAX; ++k) {
    const int j = seg0 + li + (k << 3);
    float val = NEGINF;
    if (j < seg1) val = fmaf(f[j], inv2, lcg) + (float)Crow[j] * ninv2;
    tv[k] = val;
  }
  float m0 = NEGINF, m1 = NEGINF, m2 = NEGINF, m3 = NEGINF;
  #pragma unroll
  for (int k = 0; k < KMAX; k += 4) {
    m0 = fmaxf(m0, tv[k]); m1 = fmaxf(m1, tv[k + 1]);
    m2 = fmaxf(m2, tv[k + 2]); m3 = fmaxf(m3, tv[k + 3]);
  }
  float m = fmaxf(fmaxf(m0, m1), fmaxf(m2, m3));
  float s = 0.f;
  if (m != NEGINF) {
    float s0 = 0.f, s1 = 0.f, s2 = 0.f, s3 = 0.f;
    #pragma unroll
    for (int k = 0; k < KMAX; k += 4) {
      s0 += fexp2(tv[k] - m); s1 += fexp2(tv[k + 1] - m);
      s2 += fexp2(tv[k + 2] - m); s3 += fexp2(tv[k + 3] - m);
    }
    s = (s0 + s1) + (s2 + s3);
  }
  // cleanup for pathological segment lengths (> KMAX*8): normally zero iterations
  for (int j = seg0 + li + (KMAX << 3); j < seg1; j += 8)
    online1(m, s, fmaf(f[j], inv2, lcg) + (float)Crow[j] * ninv2);
  group8_lse_reduce(m, s);
  if (li == 0) {
    float r = (m == NEGINF) ? 0.f : -eps * ((m + flog2(s)) * LN2);
    gpot[(size_t)gl * NB + i] = r;
  }
}

// ---- finalize: 25 reductions -> S_g, total ----
__global__ __launch_bounds__(256) void k_final(
    const float* __restrict__ f, const float* __restrict__ gpot,
    const float* __restrict__ fxx, const float* __restrict__ fyy,
    const int* __restrict__ counts, const int* __restrict__ starts,
    float* __restrict__ out) {
  __shared__ float acc4[4];
  __shared__ float results[25];
  const int t = threadIdx.x, lane = t & 63, wid = t >> 6;
  for (int q = 0; q < 25; ++q) {
    float v = 0.f;
    if (q < 8) {
      for (int i = starts[q] + t; i < starts[q + 1]; i += 256) v += f[i];
    } else if (q < 16) {
      const int g = q - 8;
      for (int i = starts[g] + t; i < starts[g + 1]; i += 256) v += fxx[i];
    } else if (q < 24) {
      const float* gp = gpot + (size_t)(q - 16) * NB;
      for (int i = t; i < NB; i += 256) v += gp[i];
    } else {
      for (int i = t; i < NB; i += 256) v += fyy[i];
    }
    #pragma unroll
    for (int o = 32; o; o >>= 1) v += __shfl_xor(v, o);
    __syncthreads();
    if (lane == 0) acc4[wid] = v;
    __syncthreads();
    if (t == 0) results[q] = acc4[0] + acc4[1] + acc4[2] + acc4[3];
  }
  __syncthreads();
  if (t == 0) {
    const float syy = results[24] / (float)NB;
    float tot = 0.f; int nv = 0;
    float sg[8];
    for (int g = 0; g < NG; ++g) {
      float cnt = (float)(counts[g] < 1 ? 1 : counts[g]);
      float S = (results[g] - results[8 + g]) / cnt + results[16 + g] / (float)NB - syy;
      int valid = counts[g] >= 2 ? 1 : 0;
      float sv = valid ? S : 0.f;
      sg[g] = sv;
      if (valid) { tot += sv; nv++; }
    }
    tot /= (float)(nv < 1 ? 1 : nv);
    out[0] = tot;
    for (int g = 0; g < NG; ++g) out[1 + g] = sg[g];
  }
}

extern "C" void kernel_launch(void* const* d_in, const int* in_sizes, int n_in,
                              void* d_out, int out_size, void* d_ws, size_t ws_size,
                              hipStream_t stream) {
  (void)in_sizes; (void)n_in; (void)out_size; (void)ws_size;
  const float* X = (const float*)d_in[0];
  const int* sub = (const int*)d_in[1];

  char* w = (char*)d_ws;
  size_t off = 0;
  auto alloc = [&](size_t bytes) -> void* {
    void* p = w + off;
    off = (off + bytes + 255) & ~(size_t)255;
    return p;
  };
  _Float16* C         = (_Float16*)alloc((size_t)NB * NB * 2);
  unsigned short* Xhi = (unsigned short*)alloc((size_t)NB * ND * 2);
  unsigned short* Xlo = (unsigned short*)alloc((size_t)NB * ND * 2);
  float* norms  = (float*)alloc(NB * 4);
  int*   order  = (int*)alloc(NB * 4);
  int*   pgroup = (int*)alloc(NB * 4);
  float* f      = (float*)alloc(NB * 4);
  float* gpot   = (float*)alloc((size_t)NG * NB * 4);
  float* fxx0   = (float*)alloc(NB * 4);
  float* fxx1   = (float*)alloc(NB * 4);
  float* fyy0   = (float*)alloc(NB * 4);
  float* fyy1   = (float*)alloc(NB * 4);
  int*   counts = (int*)alloc(NG * 4);
  int*   starts = (int*)alloc((NG + 1) * 4);
  float* lc2    = (float*)alloc(NG * 4);
  unsigned int* cmax = (unsigned int*)alloc(4);

  k_setup<<<1, 256, 0, stream>>>(sub, order, pgroup, counts, starts, lc2, cmax,
                                 gpot, f, fxx0, fyy0);
  k_permute<<<NB, 128, 0, stream>>>(X, order, Xhi, Xlo, norms);
  k_gemm<<<dim3(16, 16), 256, 0, stream>>>(Xhi, Xlo, norms, C, cmax);
  for (int it = 0; it < NITER; ++it) {
    float* fxi = (it & 1) ? fxx1 : fxx0;
    float* fxo = (it & 1) ? fxx0 : fxx1;
    float* fyi = (it & 1) ? fyy1 : fyy0;
    float* fyo = (it & 1) ? fyy0 : fyy1;
    k_pass1<<<NB / 4, 256, 0, stream>>>(C, gpot, fxi, fyi, f, fxo, fyo,
                                        pgroup, starts, lc2, cmax, it);
    k_pass2<<<NB / 4, 256, 0, stream>>>(C, f, gpot, starts, lc2, cmax, it);
  }
  // after it=63 (odd), outputs landed in fxx0 / fyy0
  k_final<<<1, 256, 0, stream>>>(f, gpot, fxx0, fyy0, counts, starts, (float*)d_out);
}

// Round 5
// 886.343 us; speedup vs baseline: 8.8053x; 1.3950x over previous
//
#include <hip/hip_runtime.h>
#include <math.h>

#define NB 2048
#define ND 512
#define NG 8
#define NITER 64

typedef _Float16 h8 __attribute__((ext_vector_type(8)));
typedef short bf16x8 __attribute__((ext_vector_type(8)));
typedef short us4 __attribute__((ext_vector_type(4)));
typedef float f32x4 __attribute__((ext_vector_type(4)));

#define LOG2E 1.4426950408889634f
#define LN2   0.6931471805599453f
#define NEGINF (-__builtin_inff())
#define L2_09 -0.15200309344504997f  /* log2(0.9) */

__device__ __forceinline__ float fexp2(float x) { return __builtin_amdgcn_exp2f(x); }
__device__ __forceinline__ float flog2(float x) { return __builtin_amdgcn_logf(x); }

__device__ __forceinline__ unsigned short f2bf(float x) {
  unsigned u = __float_as_uint(x);
  unsigned r = u + 0x7fff + ((u >> 16) & 1);
  return (unsigned short)(r >> 16);
}
__device__ __forceinline__ float bf2f(unsigned short h) {
  return __uint_as_float(((unsigned)h) << 16);
}

__device__ __forceinline__ void online1(float& m, float& s, float t) {
  float M = fmaxf(m, t);
  s = fmaf(s, fexp2(m - M), fexp2(t - M));
  m = M;
}
__device__ __forceinline__ float wave_max(float v) {
  #pragma unroll
  for (int o = 32; o; o >>= 1) v = fmaxf(v, __shfl_xor(v, o));
  return v;
}
__device__ __forceinline__ float wave_sum(float v) {
  #pragma unroll
  for (int o = 32; o; o >>= 1) v += __shfl_xor(v, o);
  return v;
}

// ---- inline eps schedule ----
__device__ __forceinline__ float eps_at(const unsigned int* cmax, int t) {
  float cm = __uint_as_float(*cmax);
  float diam = sqrtf(2.f * fmaxf(cm, 1e-12f));
  float sig = fmaxf(diam * fexp2((float)t * L2_09), 0.05f);
  return sig * sig;
}

// ---- setup: O(N) stable counting sort via packed 16-bit scan ----
__global__ __launch_bounds__(256) void k_setup(
    const int* __restrict__ sub_raw,
    int* __restrict__ order, int* __restrict__ pgroup,
    int* __restrict__ counts, int* __restrict__ starts,
    float* __restrict__ lc2, unsigned int* __restrict__ cmax,
    float* __restrict__ gpot, float* __restrict__ f,
    float* __restrict__ fxx0, float* __restrict__ fyy0) {
  __shared__ int subs[NB];
  __shared__ unsigned long long scanLo[256], scanHi[256];
  __shared__ int st[NG + 1];
  __shared__ int odd_nz;
  const int t = threadIdx.x;
  if (t == 0) odd_nz = 0;
  __syncthreads();
  int nz = 0;
  for (int k = t; k < 1024; k += 256) nz |= (sub_raw[2 * k + 1] != 0) ? 1 : 0;
  if (nz) atomicOr(&odd_nz, 1);
  __syncthreads();
  const int stride = odd_nz ? 1 : 2;
  for (int i = t; i < NB; i += 256) subs[i] = sub_raw[(size_t)i * stride] & 7;
  __syncthreads();
  unsigned long long cLo = 0ull, cHi = 0ull;
  #pragma unroll
  for (int k = 0; k < 8; ++k) {
    int g = subs[8 * t + k];
    unsigned long long inc = 1ull << ((g & 3) * 16);
    if (g < 4) cLo += inc; else cHi += inc;
  }
  scanLo[t] = cLo; scanHi[t] = cHi;
  __syncthreads();
  for (int s = 1; s < 256; s <<= 1) {
    unsigned long long aLo = (t >= s) ? scanLo[t - s] : 0ull;
    unsigned long long aHi = (t >= s) ? scanHi[t - s] : 0ull;
    __syncthreads();
    scanLo[t] += aLo; scanHi[t] += aHi;
    __syncthreads();
  }
  if (t == 0) {
    unsigned long long TLo = scanLo[255], THi = scanHi[255];
    int a = 0;
    for (int g = 0; g < NG; ++g) {
      st[g] = a;
      a += (int)(((g < 4 ? TLo : THi) >> ((g & 3) * 16)) & 0xffffull);
    }
    st[NG] = a;
  }
  __syncthreads();
  unsigned long long bLo = t ? scanLo[t - 1] : 0ull;
  unsigned long long bHi = t ? scanHi[t - 1] : 0ull;
  #pragma unroll
  for (int k = 0; k < 8; ++k) {
    int idx = 8 * t + k;
    int g = subs[idx];
    int sh = (g & 3) * 16;
    unsigned long long cur = (g < 4) ? bLo : bHi;
    int r = (int)((cur >> sh) & 0xffffull);
    int pos = st[g] + r;
    order[pos] = idx;
    pgroup[pos] = g;
    if (g < 4) bLo += 1ull << sh; else bHi += 1ull << sh;
  }
  if (t < NG) {
    int c = st[t + 1] - st[t];
    counts[t] = c;
    int cc = c < 1 ? 1 : c;
    lc2[t] = -flog2((float)cc);
  }
  if (t < NG + 1) starts[t] = st[t];
  if (t == 0) *cmax = 0u;
  {
    float4* g4 = (float4*)gpot;
    for (int i = t; i < NG * NB / 4; i += 256) g4[i] = make_float4(0.f, 0.f, 0.f, 0.f);
  }
  for (int i = t; i < NB; i += 256) { f[i] = 0.f; fxx0[i] = 0.f; fyy0[i] = 0.f; }
}

// ---- permute + split into bf16 hi/lo + row norms (norms from exact f32) ----
__global__ __launch_bounds__(128) void k_permute(
    const float* __restrict__ X, const int* __restrict__ order,
    unsigned short* __restrict__ Xhi, unsigned short* __restrict__ Xlo,
    float* __restrict__ norms) {
  const int i = blockIdx.x, t = threadIdx.x;
  const int src = order[i];
  float4 v = ((const float4*)(X + (size_t)src * ND))[t];
  float vv[4] = {v.x, v.y, v.z, v.w};
  unsigned short h[4], l[4];
  #pragma unroll
  for (int e = 0; e < 4; ++e) {
    h[e] = f2bf(vv[e]);
    l[e] = f2bf(vv[e] - bf2f(h[e]));
  }
  us4 hv = { (short)h[0], (short)h[1], (short)h[2], (short)h[3] };
  us4 lv = { (short)l[0], (short)l[1], (short)l[2], (short)l[3] };
  *(us4*)(Xhi + (size_t)i * ND + t * 4) = hv;
  *(us4*)(Xlo + (size_t)i * ND + t * 4) = lv;
  float ss = v.x * v.x + v.y * v.y + v.z * v.z + v.w * v.w;
  #pragma unroll
  for (int o = 32; o; o >>= 1) ss += __shfl_xor(ss, o);
  __shared__ float p[2];
  if ((t & 63) == 0) p[t >> 6] = ss;
  __syncthreads();
  if (t == 0) norms[i] = p[0] + p[1];
}

// ---- C = fp16(0.5*relu(n_i + n_j - 2 X X^T)) via split-bf16 MFMA + global max ----
__global__ __launch_bounds__(256, 1) void k_gemm(
    const unsigned short* __restrict__ Xhi, const unsigned short* __restrict__ Xlo,
    const float* __restrict__ norms, _Float16* __restrict__ C,
    unsigned int* __restrict__ cmax) {
  __shared__ unsigned short Ah[128][40], Al[128][40], Bh[128][40], Bl[128][40];
  const int t = threadIdx.x;
  const int wave = t >> 6, lane = t & 63;
  const int wm = wave >> 1, wn = wave & 1;
  const int i0 = blockIdx.y * 128, j0 = blockIdx.x * 128;
  const int srow = t >> 1, shalf = t & 1;
  const size_t gAoff = (size_t)(i0 + srow) * ND + shalf * 16;
  const size_t gBoff = (size_t)(j0 + srow) * ND + shalf * 16;
  const int fr = lane & 15, fo = (lane >> 4) * 8;

  f32x4 acc[4][4];
  #pragma unroll
  for (int mi = 0; mi < 4; ++mi)
    #pragma unroll
    for (int ni = 0; ni < 4; ++ni) acc[mi][ni] = (f32x4){0.f, 0.f, 0.f, 0.f};

  for (int kc = 0; kc < ND; kc += 32) {
    bf16x8 a0 = *(const bf16x8*)(Xhi + gAoff + kc);
    bf16x8 a1 = *(const bf16x8*)(Xhi + gAoff + kc + 8);
    bf16x8 a2 = *(const bf16x8*)(Xlo + gAoff + kc);
    bf16x8 a3 = *(const bf16x8*)(Xlo + gAoff + kc + 8);
    bf16x8 b0 = *(const bf16x8*)(Xhi + gBoff + kc);
    bf16x8 b1 = *(const bf16x8*)(Xhi + gBoff + kc + 8);
    bf16x8 b2 = *(const bf16x8*)(Xlo + gBoff + kc);
    bf16x8 b3 = *(const bf16x8*)(Xlo + gBoff + kc + 8);
    *(bf16x8*)&Ah[srow][shalf * 16] = a0;
    *(bf16x8*)&Ah[srow][shalf * 16 + 8] = a1;
    *(bf16x8*)&Al[srow][shalf * 16] = a2;
    *(bf16x8*)&Al[srow][shalf * 16 + 8] = a3;
    *(bf16x8*)&Bh[srow][shalf * 16] = b0;
    *(bf16x8*)&Bh[srow][shalf * 16 + 8] = b1;
    *(bf16x8*)&Bl[srow][shalf * 16] = b2;
    *(bf16x8*)&Bl[srow][shalf * 16 + 8] = b3;
    __syncthreads();

    bf16x8 fah[4], fal[4], fbh[4], fbl[4];
    #pragma unroll
    for (int mi = 0; mi < 4; ++mi) {
      fah[mi] = *(const bf16x8*)&Ah[wm * 64 + mi * 16 + fr][fo];
      fal[mi] = *(const bf16x8*)&Al[wm * 64 + mi * 16 + fr][fo];
    }
    #pragma unroll
    for (int ni = 0; ni < 4; ++ni) {
      fbh[ni] = *(const bf16x8*)&Bh[wn * 64 + ni * 16 + fr][fo];
      fbl[ni] = *(const bf16x8*)&Bl[wn * 64 + ni * 16 + fr][fo];
    }
    #pragma unroll
    for (int mi = 0; mi < 4; ++mi)
      #pragma unroll
      for (int ni = 0; ni < 4; ++ni) {
        acc[mi][ni] = __builtin_amdgcn_mfma_f32_16x16x32_bf16(fah[mi], fbh[ni], acc[mi][ni], 0, 0, 0);
        acc[mi][ni] = __builtin_amdgcn_mfma_f32_16x16x32_bf16(fah[mi], fbl[ni], acc[mi][ni], 0, 0, 0);
        acc[mi][ni] = __builtin_amdgcn_mfma_f32_16x16x32_bf16(fal[mi], fbh[ni], acc[mi][ni], 0, 0, 0);
      }
    __syncthreads();
  }

  const int dr = (lane >> 4) * 4, dc = lane & 15;
  float njn[4];
  #pragma unroll
  for (int ni = 0; ni < 4; ++ni) njn[ni] = norms[j0 + wn * 64 + ni * 16 + dc];
  float lmax = 0.f;
  #pragma unroll
  for (int mi = 0; mi < 4; ++mi) {
    const int rbase = i0 + wm * 64 + mi * 16 + dr;
    float4 nin = *(const float4*)(norms + rbase);
    float nin4[4] = {nin.x, nin.y, nin.z, nin.w};
    #pragma unroll
    for (int ni = 0; ni < 4; ++ni) {
      const int cbase = j0 + wn * 64 + ni * 16 + dc;
      #pragma unroll
      for (int reg = 0; reg < 4; ++reg) {
        float v = 0.5f * fmaxf(nin4[reg] + njn[ni] - 2.f * acc[mi][ni][reg], 0.f);
        C[(size_t)(rbase + reg) * NB + cbase] = (_Float16)v;
        lmax = fmaxf(lmax, v);
      }
    }
  }
  lmax = wave_max(lmax);
  __shared__ float wmax[4];
  if (lane == 0) wmax[wave] = lmax;
  __syncthreads();
  if (t == 0) {
    float m = fmaxf(fmaxf(wmax[0], wmax[1]), fmaxf(wmax[2], wmax[3]));
    atomicMax(cmax, __float_as_uint(m));
  }
}

// ---- pass1: one BLOCK per row; 256 threads x 8 cols; block max-then-sum ----
__global__ __launch_bounds__(256) void k_pass1(
    const _Float16* __restrict__ C, const float* __restrict__ gpot,
    const float* __restrict__ fxx_in, const float* __restrict__ fyy_in,
    float* __restrict__ f_out, float* __restrict__ fxx_out, float* __restrict__ fyy_out,
    const int* __restrict__ pgroup, const int* __restrict__ starts,
    const float* __restrict__ lc2, const unsigned int* __restrict__ cmax, int iter) {
  const int i = blockIdx.x;
  const int t = threadIdx.x, lane = t & 63, wid = t >> 6;
  const float eps = eps_at(cmax, iter);
  const float inv2 = LOG2E / eps;
  const float ninv2 = -inv2;
  const int gi = pgroup[i];
  const float lb2 = -11.0f;  // -log2(2048)
  const _Float16* Crow = C + (size_t)i * NB;
  const float* gr = gpot + (size_t)gi * NB;

  // 8 columns per thread
  const int j0 = t * 8;
  h8 ch = *(const h8*)(Crow + j0);
  float4 g0 = *(const float4*)(gr + j0);
  float4 g1 = *(const float4*)(gr + j0 + 4);
  float4 y0 = *(const float4*)(fyy_in + j0);
  float4 y1 = *(const float4*)(fyy_in + j0 + 4);
  float gv[8] = {g0.x, g0.y, g0.z, g0.w, g1.x, g1.y, g1.z, g1.w};
  float yv[8] = {y0.x, y0.y, y0.z, y0.w, y1.x, y1.y, y1.z, y1.w};
  float tA[8], tY[8];
  #pragma unroll
  for (int e = 0; e < 8; ++e) {
    float ci = fmaf((float)ch[e], ninv2, lb2);
    tA[e] = fmaf(gv[e], inv2, ci);
    tY[e] = fmaf(yv[e], inv2, ci);
  }
  float lmA = fmaxf(fmaxf(fmaxf(tA[0], tA[1]), fmaxf(tA[2], tA[3])),
                    fmaxf(fmaxf(tA[4], tA[5]), fmaxf(tA[6], tA[7])));
  float lmY = fmaxf(fmaxf(fmaxf(tY[0], tY[1]), fmaxf(tY[2], tY[3])),
                    fmaxf(fmaxf(tY[4], tY[5]), fmaxf(tY[6], tY[7])));

  // fxx: own segment, 1 col per thread (stride 256)
  const float lcg = lc2[gi];
  const int seg0 = starts[gi], seg1 = starts[gi + 1];
  float mXl = NEGINF, sXl = 0.f;
  for (int j = seg0 + t; j < seg1; j += 256)
    online1(mXl, sXl, fmaf(fxx_in[j], inv2, lcg) + (float)Crow[j] * ninv2);

  // block max reduce (3 channels, one LDS round-trip)
  __shared__ float rA[4], rB[4], rC[4], rA2[4], rB2[4], rC2[4];
  float wmA = wave_max(lmA), wmY = wave_max(lmY), wmX = wave_max(mXl);
  if (lane == 0) { rA[wid] = wmA; rB[wid] = wmY; rC[wid] = wmX; }
  __syncthreads();
  const float mA = fmaxf(fmaxf(rA[0], rA[1]), fmaxf(rA[2], rA[3]));
  const float mY = fmaxf(fmaxf(rB[0], rB[1]), fmaxf(rB[2], rB[3]));
  const float mX = fmaxf(fmaxf(rC[0], rC[1]), fmaxf(rC[2], rC[3]));

  // independent exp2 sums with block max
  float sA = 0.f, sY = 0.f;
  #pragma unroll
  for (int e = 0; e < 8; ++e) {
    sA += fexp2(tA[e] - mA);
    sY += fexp2(tY[e] - mY);
  }
  float sX = (mXl == NEGINF) ? 0.f : sXl * fexp2(mXl - mX);
  float wsA = wave_sum(sA), wsY = wave_sum(sY), wsX = wave_sum(sX);
  if (lane == 0) { rA2[wid] = wsA; rB2[wid] = wsY; rC2[wid] = wsX; }
  __syncthreads();
  if (t == 0) {
    const float SA = (rA2[0] + rA2[1]) + (rA2[2] + rA2[3]);
    const float SY = (rB2[0] + rB2[1]) + (rB2[2] + rB2[3]);
    const float SX = (rC2[0] + rC2[1]) + (rC2[2] + rC2[3]);
    f_out[i]   = -eps * ((mA + flog2(SA)) * LN2);
    fyy_out[i] = 0.5f * (fyy_in[i] - eps * ((mY + flog2(SY)) * LN2));
    fxx_out[i] = 0.5f * (fxx_in[i] - eps * ((mX + flog2(SX)) * LN2));
  }
}

// ---- pass2: one BLOCK per row; 8 groups x 32 lanes; max-then-sum ----
#define K2 12
__global__ __launch_bounds__(256) void k_pass2(
    const _Float16* __restrict__ C, const float* __restrict__ f,
    float* __restrict__ gpot, const int* __restrict__ starts,
    const float* __restrict__ lc2, const unsigned int* __restrict__ cmax, int iter) {
  const int i = blockIdx.x;
  const int t = threadIdx.x;
  const float eps = eps_at(cmax, iter);
  const float inv2 = LOG2E / eps;
  const float ninv2 = -inv2;
  const _Float16* Crow = C + (size_t)i * NB;
  const int gl = t >> 5, li = t & 31;
  const float lcg = lc2[gl];
  const int seg0 = starts[gl], seg1 = starts[gl + 1];

  float tv[K2];
  #pragma unroll
  for (int k = 0; k < K2; ++k) {
    const int j = seg0 + li + (k << 5);
    float val = NEGINF;
    if (j < seg1) val = fmaf(f[j], inv2, lcg) + (float)Crow[j] * ninv2;
    tv[k] = val;
  }
  float m0 = fmaxf(fmaxf(tv[0], tv[1]), fmaxf(tv[2], tv[3]));
  float m1 = fmaxf(fmaxf(tv[4], tv[5]), fmaxf(tv[6], tv[7]));
  float m2 = fmaxf(fmaxf(tv[8], tv[9]), fmaxf(tv[10], tv[11]));
  float m = fmaxf(fmaxf(m0, m1), m2);
  float s = 0.f;
  if (m != NEGINF) {
    #pragma unroll
    for (int k = 0; k < K2; ++k) s += fexp2(tv[k] - m);
  }
  // cleanup for pathological segment lengths (> K2*32): normally zero iterations
  for (int j = seg0 + li + (K2 << 5); j < seg1; j += 32)
    online1(m, s, fmaf(f[j], inv2, lcg) + (float)Crow[j] * ninv2);

  // 32-lane LSE reduce
  float M = m;
  #pragma unroll
  for (int o = 16; o; o >>= 1) M = fmaxf(M, __shfl_xor(M, o, 32));
  float sv = (M == NEGINF) ? 0.f : s * fexp2(m - M);
  #pragma unroll
  for (int o = 16; o; o >>= 1) sv += __shfl_xor(sv, o, 32);
  if (li == 0) {
    float r = (M == NEGINF) ? 0.f : -eps * ((M + flog2(sv)) * LN2);
    gpot[(size_t)gl * NB + i] = r;
  }
}

// ---- finalize: 25 reductions -> S_g, total ----
__global__ __launch_bounds__(256) void k_final(
    const float* __restrict__ f, const float* __restrict__ gpot,
    const float* __restrict__ fxx, const float* __restrict__ fyy,
    const int* __restrict__ counts, const int* __restrict__ starts,
    float* __restrict__ out) {
  __shared__ float acc4[4];
  __shared__ float results[25];
  const int t = threadIdx.x, lane = t & 63, wid = t >> 6;
  for (int q = 0; q < 25; ++q) {
    float v = 0.f;
    if (q < 8) {
      for (int i = starts[q] + t; i < starts[q + 1]; i += 256) v += f[i];
    } else if (q < 16) {
      const int g = q - 8;
      for (int i = starts[g] + t; i < starts[g + 1]; i += 256) v += fxx[i];
    } else if (q < 24) {
      const float* gp = gpot + (size_t)(q - 16) * NB;
      for (int i = t; i < NB; i += 256) v += gp[i];
    } else {
      for (int i = t; i < NB; i += 256) v += fyy[i];
    }
    #pragma unroll
    for (int o = 32; o; o >>= 1) v += __shfl_xor(v, o);
    __syncthreads();
    if (lane == 0) acc4[wid] = v;
    __syncthreads();
    if (t == 0) results[q] = acc4[0] + acc4[1] + acc4[2] + acc4[3];
  }
  __syncthreads();
  if (t == 0) {
    const float syy = results[24] / (float)NB;
    float tot = 0.f; int nv = 0;
    float sg[8];
    for (int g = 0; g < NG; ++g) {
      float cnt = (float)(counts[g] < 1 ? 1 : counts[g]);
      float S = (results[g] - results[8 + g]) / cnt + results[16 + g] / (float)NB - syy;
      int valid = counts[g] >= 2 ? 1 : 0;
      float sv = valid ? S : 0.f;
      sg[g] = sv;
      if (valid) { tot += sv; nv++; }
    }
    tot /= (float)(nv < 1 ? 1 : nv);
    out[0] = tot;
    for (int g = 0; g < NG; ++g) out[1 + g] = sg[g];
  }
}

extern "C" void kernel_launch(void* const* d_in, const int* in_sizes, int n_in,
                              void* d_out, int out_size, void* d_ws, size_t ws_size,
                              hipStream_t stream) {
  (void)in_sizes; (void)n_in; (void)out_size; (void)ws_size;
  const float* X = (const float*)d_in[0];
  const int* sub = (const int*)d_in[1];

  char* w = (char*)d_ws;
  size_t off = 0;
  auto alloc = [&](size_t bytes) -> void* {
    void* p = w + off;
    off = (off + bytes + 255) & ~(size_t)255;
    return p;
  };
  _Float16* C         = (_Float16*)alloc((size_t)NB * NB * 2);
  unsigned short* Xhi = (unsigned short*)alloc((size_t)NB * ND * 2);
  unsigned short* Xlo = (unsigned short*)alloc((size_t)NB * ND * 2);
  float* norms  = (float*)alloc(NB * 4);
  int*   order  = (int*)alloc(NB * 4);
  int*   pgroup = (int*)alloc(NB * 4);
  float* f      = (float*)alloc(NB * 4);
  float* gpot   = (float*)alloc((size_t)NG * NB * 4);
  float* fxx0   = (float*)alloc(NB * 4);
  float* fxx1   = (float*)alloc(NB * 4);
  float* fyy0   = (float*)alloc(NB * 4);
  float* fyy1   = (float*)alloc(NB * 4);
  int*   counts = (int*)alloc(NG * 4);
  int*   starts = (int*)alloc((NG + 1) * 4);
  float* lc2    = (float*)alloc(NG * 4);
  unsigned int* cmax = (unsigned int*)alloc(4);

  k_setup<<<1, 256, 0, stream>>>(sub, order, pgroup, counts, starts, lc2, cmax,
                                 gpot, f, fxx0, fyy0);
  k_permute<<<NB, 128, 0, stream>>>(X, order, Xhi, Xlo, norms);
  k_gemm<<<dim3(16, 16), 256, 0, stream>>>(Xhi, Xlo, norms, C, cmax);
  for (int it = 0; it < NITER; ++it) {
    float* fxi = (it & 1) ? fxx1 : fxx0;
    float* fxo = (it & 1) ? fxx0 : fxx1;
    float* fyi = (it & 1) ? fyy1 : fyy0;
    float* fyo = (it & 1) ? fyy0 : fyy1;
    k_pass1<<<NB, 256, 0, stream>>>(C, gpot, fxi, fyi, f, fxo, fyo,
                                    pgroup, starts, lc2, cmax, it);
    k_pass2<<<NB, 256, 0, stream>>>(C, f, gpot, starts, lc2, cmax, it);
  }
  // after it=63 (odd), outputs landed in fxx0 / fyy0
  k_final<<<1, 256, 0, stream>>>(f, gpot, fxx0, fyy0, counts, starts, (float*)d_out);
}

// Round 6
// 875.794 us; speedup vs baseline: 8.9114x; 1.0120x over previous
//
#include <hip/hip_runtime.h>
#include <math.h>

#define NB 2048
#define ND 512
#define NG 8
#define NITER 64

typedef _Float16 h8 __attribute__((ext_vector_type(8)));
typedef short bf16x8 __attribute__((ext_vector_type(8)));
typedef short us4 __attribute__((ext_vector_type(4)));
typedef float f32x4 __attribute__((ext_vector_type(4)));

#define LOG2E 1.4426950408889634f
#define LN2   0.6931471805599453f
#define NEGINF (-__builtin_inff())
#define L2_09 -0.15200309344504997f  /* log2(0.9) */

__device__ __forceinline__ float fexp2(float x) { return __builtin_amdgcn_exp2f(x); }
__device__ __forceinline__ float flog2(float x) { return __builtin_amdgcn_logf(x); }

__device__ __forceinline__ unsigned short f2bf(float x) {
  unsigned u = __float_as_uint(x);
  unsigned r = u + 0x7fff + ((u >> 16) & 1);
  return (unsigned short)(r >> 16);
}
__device__ __forceinline__ float bf2f(unsigned short h) {
  return __uint_as_float(((unsigned)h) << 16);
}

__device__ __forceinline__ void online1(float& m, float& s, float t) {
  float M = fmaxf(m, t);
  s = fmaf(s, fexp2(m - M), fexp2(t - M));
  m = M;
}
__device__ __forceinline__ float wave_max(float v) {
  #pragma unroll
  for (int o = 32; o; o >>= 1) v = fmaxf(v, __shfl_xor(v, o));
  return v;
}
__device__ __forceinline__ float wave_sum(float v) {
  #pragma unroll
  for (int o = 32; o; o >>= 1) v += __shfl_xor(v, o);
  return v;
}

// ---- inline eps schedule ----
__device__ __forceinline__ float eps_at(const unsigned int* cmax, int t) {
  float cm = __uint_as_float(*cmax);
  float diam = sqrtf(2.f * fmaxf(cm, 1e-12f));
  float sig = fmaxf(diam * fexp2((float)t * L2_09), 0.05f);
  return sig * sig;
}

// ---- setup: O(N) stable counting sort via packed 16-bit scan ----
__global__ __launch_bounds__(256) void k_setup(
    const int* __restrict__ sub_raw,
    int* __restrict__ order, int* __restrict__ pgroup,
    int* __restrict__ counts, int* __restrict__ starts,
    float* __restrict__ lc2, unsigned int* __restrict__ cmax,
    float* __restrict__ gpot, float* __restrict__ f,
    float* __restrict__ fxx0, float* __restrict__ fyy0) {
  __shared__ int subs[NB];
  __shared__ unsigned long long scanLo[256], scanHi[256];
  __shared__ int st[NG + 1];
  __shared__ int odd_nz;
  const int t = threadIdx.x;
  if (t == 0) odd_nz = 0;
  __syncthreads();
  int nz = 0;
  for (int k = t; k < 1024; k += 256) nz |= (sub_raw[2 * k + 1] != 0) ? 1 : 0;
  if (nz) atomicOr(&odd_nz, 1);
  __syncthreads();
  const int stride = odd_nz ? 1 : 2;
  for (int i = t; i < NB; i += 256) subs[i] = sub_raw[(size_t)i * stride] & 7;
  __syncthreads();
  unsigned long long cLo = 0ull, cHi = 0ull;
  #pragma unroll
  for (int k = 0; k < 8; ++k) {
    int g = subs[8 * t + k];
    unsigned long long inc = 1ull << ((g & 3) * 16);
    if (g < 4) cLo += inc; else cHi += inc;
  }
  scanLo[t] = cLo; scanHi[t] = cHi;
  __syncthreads();
  for (int s = 1; s < 256; s <<= 1) {
    unsigned long long aLo = (t >= s) ? scanLo[t - s] : 0ull;
    unsigned long long aHi = (t >= s) ? scanHi[t - s] : 0ull;
    __syncthreads();
    scanLo[t] += aLo; scanHi[t] += aHi;
    __syncthreads();
  }
  if (t == 0) {
    unsigned long long TLo = scanLo[255], THi = scanHi[255];
    int a = 0;
    for (int g = 0; g < NG; ++g) {
      st[g] = a;
      a += (int)(((g < 4 ? TLo : THi) >> ((g & 3) * 16)) & 0xffffull);
    }
    st[NG] = a;
  }
  __syncthreads();
  unsigned long long bLo = t ? scanLo[t - 1] : 0ull;
  unsigned long long bHi = t ? scanHi[t - 1] : 0ull;
  #pragma unroll
  for (int k = 0; k < 8; ++k) {
    int idx = 8 * t + k;
    int g = subs[idx];
    int sh = (g & 3) * 16;
    unsigned long long cur = (g < 4) ? bLo : bHi;
    int r = (int)((cur >> sh) & 0xffffull);
    int pos = st[g] + r;
    order[pos] = idx;
    pgroup[pos] = g;
    if (g < 4) bLo += 1ull << sh; else bHi += 1ull << sh;
  }
  if (t < NG) {
    int c = st[t + 1] - st[t];
    counts[t] = c;
    int cc = c < 1 ? 1 : c;
    lc2[t] = -flog2((float)cc);
  }
  if (t < NG + 1) starts[t] = st[t];
  if (t == 0) *cmax = 0u;
  {
    float4* g4 = (float4*)gpot;
    for (int i = t; i < NG * NB / 4; i += 256) g4[i] = make_float4(0.f, 0.f, 0.f, 0.f);
  }
  for (int i = t; i < NB; i += 256) { f[i] = 0.f; fxx0[i] = 0.f; fyy0[i] = 0.f; }
}

// ---- permute + split into bf16 hi/lo + row norms (norms from exact f32) ----
__global__ __launch_bounds__(128) void k_permute(
    const float* __restrict__ X, const int* __restrict__ order,
    unsigned short* __restrict__ Xhi, unsigned short* __restrict__ Xlo,
    float* __restrict__ norms) {
  const int i = blockIdx.x, t = threadIdx.x;
  const int src = order[i];
  float4 v = ((const float4*)(X + (size_t)src * ND))[t];
  float vv[4] = {v.x, v.y, v.z, v.w};
  unsigned short h[4], l[4];
  #pragma unroll
  for (int e = 0; e < 4; ++e) {
    h[e] = f2bf(vv[e]);
    l[e] = f2bf(vv[e] - bf2f(h[e]));
  }
  us4 hv = { (short)h[0], (short)h[1], (short)h[2], (short)h[3] };
  us4 lv = { (short)l[0], (short)l[1], (short)l[2], (short)l[3] };
  *(us4*)(Xhi + (size_t)i * ND + t * 4) = hv;
  *(us4*)(Xlo + (size_t)i * ND + t * 4) = lv;
  float ss = v.x * v.x + v.y * v.y + v.z * v.z + v.w * v.w;
  #pragma unroll
  for (int o = 32; o; o >>= 1) ss += __shfl_xor(ss, o);
  __shared__ float p[2];
  if ((t & 63) == 0) p[t >> 6] = ss;
  __syncthreads();
  if (t == 0) norms[i] = p[0] + p[1];
}

// ---- C = fp16(0.5*relu(n_i + n_j - 2 X X^T)) via split-bf16 MFMA + global max ----
__global__ __launch_bounds__(256, 1) void k_gemm(
    const unsigned short* __restrict__ Xhi, const unsigned short* __restrict__ Xlo,
    const float* __restrict__ norms, _Float16* __restrict__ C,
    unsigned int* __restrict__ cmax) {
  __shared__ unsigned short Ah[128][40], Al[128][40], Bh[128][40], Bl[128][40];
  const int t = threadIdx.x;
  const int wave = t >> 6, lane = t & 63;
  const int wm = wave >> 1, wn = wave & 1;
  const int i0 = blockIdx.y * 128, j0 = blockIdx.x * 128;
  const int srow = t >> 1, shalf = t & 1;
  const size_t gAoff = (size_t)(i0 + srow) * ND + shalf * 16;
  const size_t gBoff = (size_t)(j0 + srow) * ND + shalf * 16;
  const int fr = lane & 15, fo = (lane >> 4) * 8;

  f32x4 acc[4][4];
  #pragma unroll
  for (int mi = 0; mi < 4; ++mi)
    #pragma unroll
    for (int ni = 0; ni < 4; ++ni) acc[mi][ni] = (f32x4){0.f, 0.f, 0.f, 0.f};

  for (int kc = 0; kc < ND; kc += 32) {
    bf16x8 a0 = *(const bf16x8*)(Xhi + gAoff + kc);
    bf16x8 a1 = *(const bf16x8*)(Xhi + gAoff + kc + 8);
    bf16x8 a2 = *(const bf16x8*)(Xlo + gAoff + kc);
    bf16x8 a3 = *(const bf16x8*)(Xlo + gAoff + kc + 8);
    bf16x8 b0 = *(const bf16x8*)(Xhi + gBoff + kc);
    bf16x8 b1 = *(const bf16x8*)(Xhi + gBoff + kc + 8);
    bf16x8 b2 = *(const bf16x8*)(Xlo + gBoff + kc);
    bf16x8 b3 = *(const bf16x8*)(Xlo + gBoff + kc + 8);
    *(bf16x8*)&Ah[srow][shalf * 16] = a0;
    *(bf16x8*)&Ah[srow][shalf * 16 + 8] = a1;
    *(bf16x8*)&Al[srow][shalf * 16] = a2;
    *(bf16x8*)&Al[srow][shalf * 16 + 8] = a3;
    *(bf16x8*)&Bh[srow][shalf * 16] = b0;
    *(bf16x8*)&Bh[srow][shalf * 16 + 8] = b1;
    *(bf16x8*)&Bl[srow][shalf * 16] = b2;
    *(bf16x8*)&Bl[srow][shalf * 16 + 8] = b3;
    __syncthreads();

    bf16x8 fah[4], fal[4], fbh[4], fbl[4];
    #pragma unroll
    for (int mi = 0; mi < 4; ++mi) {
      fah[mi] = *(const bf16x8*)&Ah[wm * 64 + mi * 16 + fr][fo];
      fal[mi] = *(const bf16x8*)&Al[wm * 64 + mi * 16 + fr][fo];
    }
    #pragma unroll
    for (int ni = 0; ni < 4; ++ni) {
      fbh[ni] = *(const bf16x8*)&Bh[wn * 64 + ni * 16 + fr][fo];
      fbl[ni] = *(const bf16x8*)&Bl[wn * 64 + ni * 16 + fr][fo];
    }
    #pragma unroll
    for (int mi = 0; mi < 4; ++mi)
      #pragma unroll
      for (int ni = 0; ni < 4; ++ni) {
        acc[mi][ni] = __builtin_amdgcn_mfma_f32_16x16x32_bf16(fah[mi], fbh[ni], acc[mi][ni], 0, 0, 0);
        acc[mi][ni] = __builtin_amdgcn_mfma_f32_16x16x32_bf16(fah[mi], fbl[ni], acc[mi][ni], 0, 0, 0);
        acc[mi][ni] = __builtin_amdgcn_mfma_f32_16x16x32_bf16(fal[mi], fbh[ni], acc[mi][ni], 0, 0, 0);
      }
    __syncthreads();
  }

  const int dr = (lane >> 4) * 4, dc = lane & 15;
  float njn[4];
  #pragma unroll
  for (int ni = 0; ni < 4; ++ni) njn[ni] = norms[j0 + wn * 64 + ni * 16 + dc];
  float lmax = 0.f;
  #pragma unroll
  for (int mi = 0; mi < 4; ++mi) {
    const int rbase = i0 + wm * 64 + mi * 16 + dr;
    float4 nin = *(const float4*)(norms + rbase);
    float nin4[4] = {nin.x, nin.y, nin.z, nin.w};
    #pragma unroll
    for (int ni = 0; ni < 4; ++ni) {
      const int cbase = j0 + wn * 64 + ni * 16 + dc;
      #pragma unroll
      for (int reg = 0; reg < 4; ++reg) {
        float v = 0.5f * fmaxf(nin4[reg] + njn[ni] - 2.f * acc[mi][ni][reg], 0.f);
        C[(size_t)(rbase + reg) * NB + cbase] = (_Float16)v;
        lmax = fmaxf(lmax, v);
      }
    }
  }
  lmax = wave_max(lmax);
  __shared__ float wmax[4];
  if (lane == 0) wmax[wave] = lmax;
  __syncthreads();
  if (t == 0) {
    float m = fmaxf(fmaxf(wmax[0], wmax[1]), fmaxf(wmax[2], wmax[3]));
    atomicMax(cmax, __float_as_uint(m));
  }
}

// ---- pass1: one BLOCK per row; 256 threads x 8 cols; block max-then-sum ----
__global__ __launch_bounds__(256) void k_pass1(
    const _Float16* __restrict__ C, const float* __restrict__ gpot,
    const float* __restrict__ fxx_in, const float* __restrict__ fyy_in,
    float* __restrict__ f_out, float* __restrict__ fxx_out, float* __restrict__ fyy_out,
    const int* __restrict__ pgroup, const int* __restrict__ starts,
    const float* __restrict__ lc2, const unsigned int* __restrict__ cmax, int iter) {
  const int i = blockIdx.x;
  const int t = threadIdx.x, lane = t & 63, wid = t >> 6;
  // hoist scalar loads used only at the end
  const float fyi_i = fyy_in[i];
  const float fxi_i = fxx_in[i];
  const float eps = eps_at(cmax, iter);
  const float inv2 = LOG2E / eps;
  const float ninv2 = -inv2;
  const int gi = pgroup[i];
  const float lb2 = -11.0f;  // -log2(2048)
  const _Float16* Crow = C + (size_t)i * NB;
  const float* gr = gpot + (size_t)gi * NB;

  // 8 columns per thread
  const int j0 = t * 8;
  h8 ch = *(const h8*)(Crow + j0);
  float4 g0 = *(const float4*)(gr + j0);
  float4 g1 = *(const float4*)(gr + j0 + 4);
  float4 y0 = *(const float4*)(fyy_in + j0);
  float4 y1 = *(const float4*)(fyy_in + j0 + 4);
  float gv[8] = {g0.x, g0.y, g0.z, g0.w, g1.x, g1.y, g1.z, g1.w};
  float yv[8] = {y0.x, y0.y, y0.z, y0.w, y1.x, y1.y, y1.z, y1.w};
  float tA[8], tY[8];
  #pragma unroll
  for (int e = 0; e < 8; ++e) {
    float ci = fmaf((float)ch[e], ninv2, lb2);
    tA[e] = fmaf(gv[e], inv2, ci);
    tY[e] = fmaf(yv[e], inv2, ci);
  }
  float lmA = fmaxf(fmaxf(fmaxf(tA[0], tA[1]), fmaxf(tA[2], tA[3])),
                    fmaxf(fmaxf(tA[4], tA[5]), fmaxf(tA[6], tA[7])));
  float lmY = fmaxf(fmaxf(fmaxf(tY[0], tY[1]), fmaxf(tY[2], tY[3])),
                    fmaxf(fmaxf(tY[4], tY[5]), fmaxf(tY[6], tY[7])));

  // fxx: own segment, 1 col per thread (stride 256)
  const float lcg = lc2[gi];
  const int seg0 = starts[gi], seg1 = starts[gi + 1];
  float mXl = NEGINF, sXl = 0.f;
  for (int j = seg0 + t; j < seg1; j += 256)
    online1(mXl, sXl, fmaf(fxx_in[j], inv2, lcg) + (float)Crow[j] * ninv2);

  // block max reduce (3 channels, one LDS round-trip)
  __shared__ float rA[4], rB[4], rC[4], rA2[4], rB2[4], rC2[4];
  float wmA = wave_max(lmA), wmY = wave_max(lmY), wmX = wave_max(mXl);
  if (lane == 0) { rA[wid] = wmA; rB[wid] = wmY; rC[wid] = wmX; }
  __syncthreads();
  const float mA = fmaxf(fmaxf(rA[0], rA[1]), fmaxf(rA[2], rA[3]));
  const float mY = fmaxf(fmaxf(rB[0], rB[1]), fmaxf(rB[2], rB[3]));
  const float mX = fmaxf(fmaxf(rC[0], rC[1]), fmaxf(rC[2], rC[3]));

  // independent exp2 sums with block max
  float sA = 0.f, sY = 0.f;
  #pragma unroll
  for (int e = 0; e < 8; ++e) {
    sA += fexp2(tA[e] - mA);
    sY += fexp2(tY[e] - mY);
  }
  float sX = (mXl == NEGINF) ? 0.f : sXl * fexp2(mXl - mX);
  float wsA = wave_sum(sA), wsY = wave_sum(sY), wsX = wave_sum(sX);
  if (lane == 0) { rA2[wid] = wsA; rB2[wid] = wsY; rC2[wid] = wsX; }
  __syncthreads();
  if (t == 0) {
    const float SA = (rA2[0] + rA2[1]) + (rA2[2] + rA2[3]);
    const float SY = (rB2[0] + rB2[1]) + (rB2[2] + rB2[3]);
    const float SX = (rC2[0] + rC2[1]) + (rC2[2] + rC2[3]);
    f_out[i]   = -eps * ((mA + flog2(SA)) * LN2);
    fyy_out[i] = 0.5f * (fyi_i - eps * ((mY + flog2(SY)) * LN2));
    fxx_out[i] = 0.5f * (fxi_i - eps * ((mX + flog2(SX)) * LN2));
  }
}

// ---- pass2: one BLOCK per row; 8 groups x 32 lanes; vectorized segment loads ----
__global__ __launch_bounds__(256) void k_pass2(
    const _Float16* __restrict__ C, const float* __restrict__ f,
    float* __restrict__ gpot, const int* __restrict__ starts,
    const float* __restrict__ lc2, const unsigned int* __restrict__ cmax, int iter) {
  const int i = blockIdx.x;
  const int t = threadIdx.x;
  const float eps = eps_at(cmax, iter);
  const float inv2 = LOG2E / eps;
  const float ninv2 = -inv2;
  const _Float16* Crow = C + (size_t)i * NB;
  const int gl = t >> 5, li = t & 31;
  const float lcg = lc2[gl];
  const int seg0 = starts[gl], seg1 = starts[gl + 1];
  const int a0 = (seg0 + 7) & ~7;   // aligned vector start
  const int a1 = seg1 & ~7;          // aligned vector end

  // vector body: lane li covers 8 contiguous cols per k-step
  float tv[16];
  #pragma unroll
  for (int k = 0; k < 16; ++k) tv[k] = NEGINF;
  #pragma unroll
  for (int k = 0; k < 2; ++k) {
    const int j = a0 + (li + k * 32) * 8;
    if (j + 8 <= a1) {
      h8 ch = *(const h8*)(Crow + j);
      float4 f0 = *(const float4*)(f + j);
      float4 f1 = *(const float4*)(f + j + 4);
      float fv[8] = {f0.x, f0.y, f0.z, f0.w, f1.x, f1.y, f1.z, f1.w};
      #pragma unroll
      for (int e = 0; e < 8; ++e)
        tv[k * 8 + e] = fmaf(fv[e], inv2, lcg) + (float)ch[e] * ninv2;
    }
  }
  // head (< a0) and tail (>= a1) scalars, <=7 each
  float th = NEGINF, tt = NEGINF;
  {
    const int jh = seg0 + li;
    if (jh < a0 && jh < seg1)
      th = fmaf(f[jh], inv2, lcg) + (float)Crow[jh] * ninv2;
    const int jt = a1 + li;
    if (jt >= a0 && jt < seg1)
      tt = fmaf(f[jt], inv2, lcg) + (float)Crow[jt] * ninv2;
  }
  float m0 = fmaxf(fmaxf(tv[0], tv[1]), fmaxf(tv[2], tv[3]));
  float m1 = fmaxf(fmaxf(tv[4], tv[5]), fmaxf(tv[6], tv[7]));
  float m2 = fmaxf(fmaxf(tv[8], tv[9]), fmaxf(tv[10], tv[11]));
  float m3 = fmaxf(fmaxf(tv[12], tv[13]), fmaxf(tv[14], tv[15]));
  float m = fmaxf(fmaxf(fmaxf(m0, m1), fmaxf(m2, m3)), fmaxf(th, tt));
  float s = 0.f;
  if (m != NEGINF) {
    float s0 = 0.f, s1 = 0.f, s2 = 0.f, s3 = 0.f;
    #pragma unroll
    for (int k = 0; k < 16; k += 4) {
      s0 += fexp2(tv[k] - m); s1 += fexp2(tv[k + 1] - m);
      s2 += fexp2(tv[k + 2] - m); s3 += fexp2(tv[k + 3] - m);
    }
    s = ((s0 + s1) + (s2 + s3)) + (fexp2(th - m) + fexp2(tt - m));
  }
  // cleanup for pathological segments (> ~512 cols): normally zero iterations
  {
    float mc = NEGINF, sc = 0.f;
    for (int j = a0 + 512 + li; j < a1; j += 32)
      online1(mc, sc, fmaf(f[j], inv2, lcg) + (float)Crow[j] * ninv2);
    if (mc != NEGINF) {
      float M = fmaxf(m, mc);
      float sn = ((m == NEGINF) ? 0.f : s * fexp2(m - M)) + sc * fexp2(mc - M);
      m = M; s = sn;
    }
  }
  // 32-lane LSE reduce
  float M = m;
  #pragma unroll
  for (int o = 16; o; o >>= 1) M = fmaxf(M, __shfl_xor(M, o, 32));
  float sv = (m == NEGINF) ? 0.f : s * fexp2(m - M);
  #pragma unroll
  for (int o = 16; o; o >>= 1) sv += __shfl_xor(sv, o, 32);
  if (li == 0) {
    float r = (M == NEGINF) ? 0.f : -eps * ((M + flog2(sv)) * LN2);
    gpot[(size_t)gl * NB + i] = r;
  }
}

// ---- finalize: 25 reductions, wave-parallel ----
__global__ __launch_bounds__(256) void k_final(
    const float* __restrict__ f, const float* __restrict__ gpot,
    const float* __restrict__ fxx, const float* __restrict__ fyy,
    const int* __restrict__ counts, const int* __restrict__ starts,
    float* __restrict__ out) {
  __shared__ float results[25];
  const int t = threadIdx.x, lane = t & 63, wid = t >> 6;
  for (int q = wid; q < 25; q += 4) {
    float v = 0.f;
    if (q < 8) {
      for (int i = starts[q] + lane; i < starts[q + 1]; i += 64) v += f[i];
    } else if (q < 16) {
      const int g = q - 8;
      for (int i = starts[g] + lane; i < starts[g + 1]; i += 64) v += fxx[i];
    } else if (q < 24) {
      const float* gp = gpot + (size_t)(q - 16) * NB;
      for (int i = lane; i < NB; i += 64) v += gp[i];
    } else {
      for (int i = lane; i < NB; i += 64) v += fyy[i];
    }
    v = wave_sum(v);
    if (lane == 0) results[q] = v;
  }
  __syncthreads();
  if (t == 0) {
    const float syy = results[24] / (float)NB;
    float tot = 0.f; int nv = 0;
    float sg[8];
    for (int g = 0; g < NG; ++g) {
      float cnt = (float)(counts[g] < 1 ? 1 : counts[g]);
      float S = (results[g] - results[8 + g]) / cnt + results[16 + g] / (float)NB - syy;
      int valid = counts[g] >= 2 ? 1 : 0;
      float sv = valid ? S : 0.f;
      sg[g] = sv;
      if (valid) { tot += sv; nv++; }
    }
    tot /= (float)(nv < 1 ? 1 : nv);
    out[0] = tot;
    for (int g = 0; g < NG; ++g) out[1 + g] = sg[g];
  }
}

extern "C" void kernel_launch(void* const* d_in, const int* in_sizes, int n_in,
                              void* d_out, int out_size, void* d_ws, size_t ws_size,
                              hipStream_t stream) {
  (void)in_sizes; (void)n_in; (void)out_size; (void)ws_size;
  const float* X = (const float*)d_in[0];
  const int* sub = (const int*)d_in[1];

  char* w = (char*)d_ws;
  size_t off = 0;
  auto alloc = [&](size_t bytes) -> void* {
    void* p = w + off;
    off = (off + bytes + 255) & ~(size_t)255;
    return p;
  };
  _Float16* C         = (_Float16*)alloc((size_t)NB * NB * 2);
  unsigned short* Xhi = (unsigned short*)alloc((size_t)NB * ND * 2);
  unsigned short* Xlo = (unsigned short*)alloc((size_t)NB * ND * 2);
  float* norms  = (float*)alloc(NB * 4);
  int*   order  = (int*)alloc(NB * 4);
  int*   pgroup = (int*)alloc(NB * 4);
  float* f      = (float*)alloc(NB * 4);
  float* gpot   = (float*)alloc((size_t)NG * NB * 4);
  float* fxx0   = (float*)alloc(NB * 4);
  float* fxx1   = (float*)alloc(NB * 4);
  float* fyy0   = (float*)alloc(NB * 4);
  float* fyy1   = (float*)alloc(NB * 4);
  int*   counts = (int*)alloc(NG * 4);
  int*   starts = (int*)alloc((NG + 1) * 4);
  float* lc2    = (float*)alloc(NG * 4);
  unsigned int* cmax = (unsigned int*)alloc(4);

  k_setup<<<1, 256, 0, stream>>>(sub, order, pgroup, counts, starts, lc2, cmax,
                                 gpot, f, fxx0, fyy0);
  k_permute<<<NB, 128, 0, stream>>>(X, order, Xhi, Xlo, norms);
  k_gemm<<<dim3(16, 16), 256, 0, stream>>>(Xhi, Xlo, norms, C, cmax);
  for (int it = 0; it < NITER; ++it) {
    float* fxi = (it & 1) ? fxx1 : fxx0;
    float* fxo = (it & 1) ? fxx0 : fxx1;
    float* fyi = (it & 1) ? fyy1 : fyy0;
    float* fyo = (it & 1) ? fyy0 : fyy1;
    k_pass1<<<NB, 256, 0, stream>>>(C, gpot, fxi, fyi, f, fxo, fyo,
                                    pgroup, starts, lc2, cmax, it);
    k_pass2<<<NB, 256, 0, stream>>>(C, f, gpot, starts, lc2, cmax, it);
  }
  // after it=63 (odd), outputs landed in fxx0 / fyy0
  k_final<<<1, 256, 0, stream>>>(f, gpot, fxx0, fyy0, counts, starts, (float*)d_out);
}